// Round 8
// baseline (360.506 us; speedup 1.0000x reference)
//
#include <hip/hip_runtime.h>
#include <cmath>

namespace {

constexpr int NN0 = 65536;   // nodes stage 0
constexpr int NB  = 32;      // graphs
constexpr int NE  = 524288;  // edges
constexpr int FIN = 129;
constexpr int KP  = 160;     // padded K for lin0 (5 k-tiles of 32)

typedef short bf16x8 __attribute__((ext_vector_type(8)));
typedef float f32x4 __attribute__((ext_vector_type(4)));

__device__ inline float leakyrelu(float z) { return z > 0.f ? z : 0.2f * z; }
__device__ inline float eluf(float z) { return z > 0.f ? z : expm1f(z); }

__device__ inline unsigned short f2bf(float x) {
  union { float f; unsigned int u; } v; v.f = x;
  unsigned int r = v.u + 0x7fffu + ((v.u >> 16) & 1u);
  return (unsigned short)(r >> 16);
}
__device__ inline float bf2f(unsigned short h) {
  union { unsigned int u; float f; } v; v.u = ((unsigned int)h) << 16;
  return v.f;
}

__device__ inline float4 f4fma(float4 a, float c, float4 acc) {
  acc.x += a.x * c; acc.y += a.y * c; acc.z += a.z * c; acc.w += a.w * c;
  return acc;
}
__device__ inline float4 xgrp_sum(float4 v) {
#pragma unroll
  for (int off = 16; off <= 32; off <<= 1) {
    v.x += __shfl_xor(v.x, off);
    v.y += __shfl_xor(v.y, off);
    v.z += __shfl_xor(v.z, off);
    v.w += __shfl_xor(v.w, off);
  }
  return v;
}

// XCD-aware block swizzle (bijective; NB%8==0)
__device__ inline int swz_block(int bid, int bpgl) {
  int x = bid & 7;
  int local = bid >> 3;
  int g = x + ((local >> bpgl) << 3);
  return (g << bpgl) + (local & ((1 << bpgl) - 1));
}

__device__ __forceinline__ void gload_lds16(const unsigned short* g, unsigned short* l) {
  __builtin_amdgcn_global_load_lds((const unsigned int*)g, (unsigned int*)l, 16, 0, 0);
}

// ---------------- pack input x -> hi/lo bf16, K padded 129->160 -------------
__global__ void pack_x(const float* __restrict__ x,
                       unsigned short* __restrict__ xhi, unsigned short* __restrict__ xlo) {
  int idx = blockIdx.x * 256 + threadIdx.x;
  if (idx >= NN0 * KP) return;
  int row = idx / KP, c = idx - row * KP;
  float v = (c < FIN) ? x[(size_t)row * FIN + c] : 0.f;
  unsigned short h = f2bf(v);
  xhi[idx] = h;
  xlo[idx] = f2bf(v - bf2f(h));
}

// ---------------- W fragment pack: fp32 [K][256] -> hi/lo bf16 fragments ----
__global__ void pack_w(const float* __restrict__ W, int Kreal, int KT,
                       unsigned short* __restrict__ hi, unsigned short* __restrict__ lo) {
  int idx = blockIdx.x * blockDim.x + threadIdx.x;
  if (idx >= KT * 8192) return;
  int j = idx & 7;
  int lane = (idx >> 3) & 63;
  int ct = (idx >> 9) & 15;
  int kt = idx >> 13;
  int k = kt * 32 + ((lane >> 4) << 3) + j;
  int c = ct * 16 + (lane & 15);
  float v = (k < Kreal) ? W[(size_t)k * 256 + c] : 0.f;
  unsigned short h = f2bf(v);
  hi[idx] = h;
  lo[idx] = f2bf(v - bf2f(h));
}

// ---------------- pool-weight inverse norms ----------------
__global__ void pool_norms(const float* __restrict__ w0, const float* __restrict__ w1,
                           float* __restrict__ norms) {
  int lane = threadIdx.x;
  float a0 = 0.f, a1 = 0.f;
#pragma unroll
  for (int j = lane; j < 256; j += 64) {
    float v0 = w0[j]; a0 += v0 * v0;
    float v1 = w1[j]; a1 += v1 * v1;
  }
#pragma unroll
  for (int off = 32; off >= 1; off >>= 1) {
    a0 += __shfl_xor(a0, off);
    a1 += __shfl_xor(a1, off);
  }
  if (lane == 0) {
    norms[0] = 1.f / (sqrtf(a0) + 1e-16f);
    norms[1] = 1.f / (sqrtf(a1) + 1e-16f);
  }
}

// ---------------- FUSED lin0 + GAT0 GEMM ----------------
// Stage 1: h = ReLU(X@W0 + b0) for a 64x256 tile -> LDS (bf16 hi/lo, XOR-swizzled).
// Stage 2: hW = h@W1 from LDS, fp32 out + fused a_s/a_d head reductions.
template <int KT0>
__global__ __launch_bounds__(256, 2) void gemm_fused(
    const unsigned short* __restrict__ Xhi, const unsigned short* __restrict__ Xlo,
    int ldx,
    const unsigned short* __restrict__ B0hi, const unsigned short* __restrict__ B0lo,
    const float* __restrict__ bias0,
    const unsigned short* __restrict__ B1hi, const unsigned short* __restrict__ B1lo,
    float* __restrict__ Out,
    const float* __restrict__ attsrc, const float* __restrict__ attdst,
    float* __restrict__ a_s, float* __restrict__ a_d) {
  __shared__ __align__(16) unsigned short As[2][2][64][32];  // 16 KB staging
  __shared__ __align__(16) char Hsh[2][64 * 512];            // 64 KB h-tile hi/lo
  const int tid = threadIdx.x;
  const int lane = tid & 63;
  const int w = tid >> 6;
  const int row0 = blockIdx.x * 64;
  const int l15 = lane & 15, q = lane >> 4;
  const int srow = w * 16 + (lane >> 2);
  const int skc = (lane & 3) * 8;

  auto stage = [&](int nb, int kt) {
    const size_t goff = (size_t)(row0 + srow) * ldx + kt * 32 + skc;
    gload_lds16(Xhi + goff, &As[nb][0][w * 16][0]);
    gload_lds16(Xlo + goff, &As[nb][1][w * 16][0]);
  };

  f32x4 acc[4][4];
#pragma unroll
  for (int mf = 0; mf < 4; mf++)
#pragma unroll
    for (int nf = 0; nf < 4; nf++) acc[mf][nf] = (f32x4)(0.f);

  stage(0, 0);
  __syncthreads();

  // ---- stage 1: X @ W0 ----
#pragma unroll
  for (int kt = 0; kt < KT0; ++kt) {
    const int nb = kt & 1;
    if (kt + 1 < KT0) stage(nb ^ 1, kt + 1);
    bf16x8 bh[4], bl[4];
#pragma unroll
    for (int nf = 0; nf < 4; nf++) {
      const int ct = w * 4 + nf;
      const size_t bbase = ((size_t)((kt * 16 + ct) * 64 + lane)) << 3;
      bh[nf] = *reinterpret_cast<const bf16x8*>(B0hi + bbase);
      bl[nf] = *reinterpret_cast<const bf16x8*>(B0lo + bbase);
    }
    bf16x8 ah[4], al[4];
#pragma unroll
    for (int mf = 0; mf < 4; mf++) {
      const int ar = mf * 16 + l15;
      ah[mf] = *reinterpret_cast<const bf16x8*>(&As[nb][0][ar][q * 8]);
      al[mf] = *reinterpret_cast<const bf16x8*>(&As[nb][1][ar][q * 8]);
    }
#pragma unroll
    for (int mf = 0; mf < 4; mf++)
#pragma unroll
      for (int nf = 0; nf < 4; nf++) {
        acc[mf][nf] = __builtin_amdgcn_mfma_f32_16x16x32_bf16(ah[mf], bh[nf], acc[mf][nf], 0, 0, 0);
        acc[mf][nf] = __builtin_amdgcn_mfma_f32_16x16x32_bf16(ah[mf], bl[nf], acc[mf][nf], 0, 0, 0);
        acc[mf][nf] = __builtin_amdgcn_mfma_f32_16x16x32_bf16(al[mf], bh[nf], acc[mf][nf], 0, 0, 0);
      }
    __syncthreads();
  }

  // ---- epilogue 1: bias + ReLU -> LDS h-tile (hi/lo, swizzled) ----
#pragma unroll
  for (int mf = 0; mf < 4; mf++) {
#pragma unroll
    for (int r = 0; r < 4; r++) {
      const int row = mf * 16 + q * 4 + r;
#pragma unroll
      for (int nf = 0; nf < 4; nf++) {
        const int col = w * 64 + nf * 16 + l15;
        float v = acc[mf][nf][r] + bias0[col];
        v = fmaxf(v, 0.f);
        unsigned short h = f2bf(v);
        unsigned short l = f2bf(v - bf2f(h));
        unsigned int off = (unsigned int)(row * 512 + col * 2) ^ ((row & 7) << 4);
        *reinterpret_cast<unsigned short*>(&Hsh[0][off]) = h;
        *reinterpret_cast<unsigned short*>(&Hsh[1][off]) = l;
        acc[mf][nf][r] = 0.f;  // reset for stage 2
      }
    }
  }
  __syncthreads();

  // ---- stage 2: h @ W1 from LDS ----
#pragma unroll
  for (int kt = 0; kt < 8; ++kt) {
    bf16x8 bh[4], bl[4];
#pragma unroll
    for (int nf = 0; nf < 4; nf++) {
      const int ct = w * 4 + nf;
      const size_t bbase = ((size_t)((kt * 16 + ct) * 64 + lane)) << 3;
      bh[nf] = *reinterpret_cast<const bf16x8*>(B1hi + bbase);
      bl[nf] = *reinterpret_cast<const bf16x8*>(B1lo + bbase);
    }
    bf16x8 ah[4], al[4];
#pragma unroll
    for (int mf = 0; mf < 4; mf++) {
      const int ar = mf * 16 + l15;
      unsigned int off = (unsigned int)(ar * 512 + kt * 64 + q * 16) ^ ((ar & 7) << 4);
      ah[mf] = *reinterpret_cast<const bf16x8*>(&Hsh[0][off]);
      al[mf] = *reinterpret_cast<const bf16x8*>(&Hsh[1][off]);
    }
#pragma unroll
    for (int mf = 0; mf < 4; mf++)
#pragma unroll
      for (int nf = 0; nf < 4; nf++) {
        acc[mf][nf] = __builtin_amdgcn_mfma_f32_16x16x32_bf16(ah[mf], bh[nf], acc[mf][nf], 0, 0, 0);
        acc[mf][nf] = __builtin_amdgcn_mfma_f32_16x16x32_bf16(ah[mf], bl[nf], acc[mf][nf], 0, 0, 0);
        acc[mf][nf] = __builtin_amdgcn_mfma_f32_16x16x32_bf16(al[mf], bh[nf], acc[mf][nf], 0, 0, 0);
      }
  }

  // ---- epilogue 2: hW out + a_s/a_d ----
#pragma unroll
  for (int mf = 0; mf < 4; mf++) {
    const int rowb = row0 + mf * 16 + q * 4;
#pragma unroll
    for (int r = 0; r < 4; r++) {
#pragma unroll
      for (int nf = 0; nf < 4; nf++) {
        const int col = w * 64 + nf * 16 + l15;
        Out[(size_t)(rowb + r) * 256 + col] = acc[mf][nf][r];
      }
    }
  }
  const int head = w;
  float sv[4], dv[4];
#pragma unroll
  for (int nf = 0; nf < 4; nf++) {
    sv[nf] = attsrc[head * 64 + nf * 16 + l15];
    dv[nf] = attdst[head * 64 + nf * 16 + l15];
  }
#pragma unroll
  for (int mf = 0; mf < 4; mf++) {
#pragma unroll
    for (int r = 0; r < 4; r++) {
      float ps = 0.f, pd = 0.f;
#pragma unroll
      for (int nf = 0; nf < 4; nf++) {
        ps += acc[mf][nf][r] * sv[nf];
        pd += acc[mf][nf][r] * dv[nf];
      }
#pragma unroll
      for (int off = 8; off >= 1; off >>= 1) {
        ps += __shfl_xor(ps, off);
        pd += __shfl_xor(pd, off);
      }
      if (l15 == 0) {
        const int row = row0 + mf * 16 + q * 4 + r;
        a_s[(size_t)row * 4 + head] = ps;
        a_d[(size_t)row * 4 + head] = pd;
      }
    }
  }
}

// ---------------- plain GEMM (GAT1) with ATT epilogue ----------------
template <int KT>
__global__ __launch_bounds__(256, 2) void gemm_att(
    const unsigned short* __restrict__ Xhi, const unsigned short* __restrict__ Xlo,
    int ldx,
    const unsigned short* __restrict__ Bhi, const unsigned short* __restrict__ Blo,
    float* __restrict__ Out,
    const float* __restrict__ attsrc, const float* __restrict__ attdst,
    float* __restrict__ a_s, float* __restrict__ a_d) {
  __shared__ __align__(16) unsigned short As[2][2][64][32];
  const int tid = threadIdx.x;
  const int lane = tid & 63;
  const int w = tid >> 6;
  const int row0 = blockIdx.x * 64;
  const int l15 = lane & 15, q = lane >> 4;
  const int srow = w * 16 + (lane >> 2);
  const int skc = (lane & 3) * 8;

  auto stage = [&](int nb, int kt) {
    const size_t goff = (size_t)(row0 + srow) * ldx + kt * 32 + skc;
    gload_lds16(Xhi + goff, &As[nb][0][w * 16][0]);
    gload_lds16(Xlo + goff, &As[nb][1][w * 16][0]);
  };

  f32x4 acc[4][4];
#pragma unroll
  for (int mf = 0; mf < 4; mf++)
#pragma unroll
    for (int nf = 0; nf < 4; nf++) acc[mf][nf] = (f32x4)(0.f);

  stage(0, 0);
  __syncthreads();

#pragma unroll
  for (int kt = 0; kt < KT; ++kt) {
    const int nb = kt & 1;
    if (kt + 1 < KT) stage(nb ^ 1, kt + 1);
    bf16x8 bh[4], bl[4];
#pragma unroll
    for (int nf = 0; nf < 4; nf++) {
      const int ct = w * 4 + nf;
      const size_t bbase = ((size_t)((kt * 16 + ct) * 64 + lane)) << 3;
      bh[nf] = *reinterpret_cast<const bf16x8*>(Bhi + bbase);
      bl[nf] = *reinterpret_cast<const bf16x8*>(Blo + bbase);
    }
    bf16x8 ah[4], al[4];
#pragma unroll
    for (int mf = 0; mf < 4; mf++) {
      const int ar = mf * 16 + l15;
      ah[mf] = *reinterpret_cast<const bf16x8*>(&As[nb][0][ar][q * 8]);
      al[mf] = *reinterpret_cast<const bf16x8*>(&As[nb][1][ar][q * 8]);
    }
#pragma unroll
    for (int mf = 0; mf < 4; mf++)
#pragma unroll
      for (int nf = 0; nf < 4; nf++) {
        acc[mf][nf] = __builtin_amdgcn_mfma_f32_16x16x32_bf16(ah[mf], bh[nf], acc[mf][nf], 0, 0, 0);
        acc[mf][nf] = __builtin_amdgcn_mfma_f32_16x16x32_bf16(ah[mf], bl[nf], acc[mf][nf], 0, 0, 0);
        acc[mf][nf] = __builtin_amdgcn_mfma_f32_16x16x32_bf16(al[mf], bh[nf], acc[mf][nf], 0, 0, 0);
      }
    __syncthreads();
  }

#pragma unroll
  for (int mf = 0; mf < 4; mf++) {
    const int rowb = row0 + mf * 16 + q * 4;
#pragma unroll
    for (int r = 0; r < 4; r++) {
#pragma unroll
      for (int nf = 0; nf < 4; nf++) {
        const int col = w * 64 + nf * 16 + l15;
        Out[(size_t)(rowb + r) * 256 + col] = acc[mf][nf][r];
      }
    }
  }
  const int head = w;
  float sv[4], dv[4];
#pragma unroll
  for (int nf = 0; nf < 4; nf++) {
    sv[nf] = attsrc[head * 64 + nf * 16 + l15];
    dv[nf] = attdst[head * 64 + nf * 16 + l15];
  }
#pragma unroll
  for (int mf = 0; mf < 4; mf++) {
#pragma unroll
    for (int r = 0; r < 4; r++) {
      float ps = 0.f, pd = 0.f;
#pragma unroll
      for (int nf = 0; nf < 4; nf++) {
        ps += acc[mf][nf][r] * sv[nf];
        pd += acc[mf][nf][r] * dv[nf];
      }
#pragma unroll
      for (int off = 8; off >= 1; off >>= 1) {
        ps += __shfl_xor(ps, off);
        pd += __shfl_xor(pd, off);
      }
      if (l15 == 0) {
        const int row = row0 + mf * 16 + q * 4 + r;
        a_s[(size_t)row * 4 + head] = ps;
        a_d[(size_t)row * 4 + head] = pd;
      }
    }
  }
}

// ---------------- stride-64 CSR scatter ----------------
__global__ void scatter0(const int* __restrict__ src, const int* __restrict__ dst,
                         int* __restrict__ cursor, int* __restrict__ csr) {
  int e = blockIdx.x * blockDim.x + threadIdx.x;
  if (e >= NE) return;
  int d = dst[e];
  int pos = atomicAdd(&cursor[d], 1);
  if (pos < 64) csr[(size_t)d * 64 + pos] = src[e];
}

__global__ void scatter1(const int* __restrict__ src, const int* __restrict__ dst,
                         const int* __restrict__ newid,
                         int* __restrict__ cursor, int* __restrict__ csr) {
  int e = blockIdx.x * blockDim.x + threadIdx.x;
  if (e >= NE) return;
  int s = newid[src[e]], d = newid[dst[e]];
  if (s < 0 || d < 0) return;
  int pos = atomicAdd(&cursor[d], 1);
  if (pos < 64) csr[(size_t)d * 64 + pos] = s;
}

// ---------------- per-graph counting sort by dim ----------------
__global__ void hist_dim(const int* __restrict__ cursor, int* __restrict__ bins,
                         int n, int lg) {
  int i = blockIdx.x * 256 + threadIdx.x;
  if (i >= n) return;
  int dim = min(cursor[i], 63) + 1;
  atomicAdd(&bins[(i >> lg) * 72 + dim], 1);
}

__global__ __launch_bounds__(64) void scan_bins(int* __restrict__ bins) {
  int g = blockIdx.x, lane = threadIdx.x;   // lane -> dim = lane+1
  int cnt = bins[g * 72 + lane + 1];
  int v = cnt;
#pragma unroll
  for (int off = 1; off < 64; off <<= 1) {
    int t = __shfl_up(v, off);
    if (lane >= off) v += t;
  }
  bins[g * 72 + lane + 1] = v - cnt;  // exclusive within graph
}

__global__ void scatter_ord(const int* __restrict__ cursor, int* __restrict__ bins,
                            int* __restrict__ order, int n, int lg) {
  int i = blockIdx.x * 256 + threadIdx.x;
  if (i >= n) return;
  int dim = min(cursor[i], 63) + 1;
  int g = i >> lg;
  int rank = atomicAdd(&bins[g * 72 + dim], 1);
  order[((size_t)g << lg) + rank] = i;
}

// --------- per-dest-node GAT: softmax + weighted sum + bias + ELU + topk score
// Nodes processed in per-graph degree-sorted order (via order[]): waves get 4
// equal-dim nodes -> dmax ~= dim; XCD swizzle preserved (sort is within-graph).
__global__ __launch_bounds__(256) void gat_node16(
    const int* __restrict__ cursor, const int* __restrict__ csr,
    const int* __restrict__ order,
    const float* __restrict__ a_s, const float* __restrict__ a_d,
    const float* __restrict__ hW, const float* __restrict__ bias,
    const float* __restrict__ pool_w, const float* __restrict__ inv_norm,
    float* __restrict__ out, float* __restrict__ score, int bpgl) {
  const int lane = threadIdx.x & 63;
  const int wv = threadIdx.x >> 6;
  const int ibase = swz_block(blockIdx.x, bpgl) * 16 + wv * 4;
  const int p = lane >> 4, l16 = lane & 15;

  const int d = order[ibase + p];
  const int deg = min(cursor[d], 63);
  const int dim = deg + 1;  // + self loop

  if (__all(dim <= 16)) {
    const float4 ad4 = *reinterpret_cast<const float4*>(&a_d[(size_t)d * 4]);
    const bool has = l16 < dim;
    int s = (l16 < deg) ? csr[(size_t)d * 64 + l16] : d;
    float4 as4 = *reinterpret_cast<const float4*>(&a_s[(size_t)s * 4]);
    float l0 = leakyrelu(as4.x + ad4.x);
    float l1 = leakyrelu(as4.y + ad4.y);
    float l2 = leakyrelu(as4.z + ad4.z);
    float l3 = leakyrelu(as4.w + ad4.w);
    float m0 = has ? l0 : -1e30f, m1 = has ? l1 : -1e30f;
    float m2 = has ? l2 : -1e30f, m3 = has ? l3 : -1e30f;
#pragma unroll
    for (int off = 1; off <= 8; off <<= 1) {
      m0 = fmaxf(m0, __shfl_xor(m0, off));
      m1 = fmaxf(m1, __shfl_xor(m1, off));
      m2 = fmaxf(m2, __shfl_xor(m2, off));
      m3 = fmaxf(m3, __shfl_xor(m3, off));
    }
    float e0 = has ? __expf(l0 - m0) : 0.f;
    float e1 = has ? __expf(l1 - m1) : 0.f;
    float e2 = has ? __expf(l2 - m2) : 0.f;
    float e3 = has ? __expf(l3 - m3) : 0.f;
    float dn0 = e0, dn1 = e1, dn2 = e2, dn3 = e3;
#pragma unroll
    for (int off = 1; off <= 8; off <<= 1) {
      dn0 += __shfl_xor(dn0, off);
      dn1 += __shfl_xor(dn1, off);
      dn2 += __shfl_xor(dn2, off);
      dn3 += __shfl_xor(dn3, off);
    }
    int dmax = dim;
    dmax = max(dmax, __shfl_xor(dmax, 16));
    dmax = max(dmax, __shfl_xor(dmax, 32));
    float4 acc[4];
#pragma unroll
    for (int h = 0; h < 4; h++) acc[h] = float4{0.f, 0.f, 0.f, 0.f};
#pragma unroll 2
    for (int t = 0; t < dmax; t++) {
      const int idx = p * 16 + t;
      int st = __shfl(s, idx);
      float c0 = __shfl(e0, idx), c1 = __shfl(e1, idx);
      float c2 = __shfl(e2, idx), c3 = __shfl(e3, idx);
      if (t < dim) {
        const float4* hp = reinterpret_cast<const float4*>(&hW[(size_t)st * 256]) + l16;
        acc[0] = f4fma(hp[0],  c0, acc[0]);
        acc[1] = f4fma(hp[16], c1, acc[1]);
        acc[2] = f4fma(hp[32], c2, acc[2]);
        acc[3] = f4fma(hp[48], c3, acc[3]);
      }
    }
    const float inv[4] = {1.f / (dn0 + 1e-16f), 1.f / (dn1 + 1e-16f),
                          1.f / (dn2 + 1e-16f), 1.f / (dn3 + 1e-16f)};
    float sd = 0.f;
#pragma unroll
    for (int h = 0; h < 4; h++) {
      const int coff = h * 64 + l16 * 4;
      float4 bb = *reinterpret_cast<const float4*>(&bias[coff]);
      float4 o;
      o.x = eluf(acc[h].x * inv[h] + bb.x);
      o.y = eluf(acc[h].y * inv[h] + bb.y);
      o.z = eluf(acc[h].z * inv[h] + bb.z);
      o.w = eluf(acc[h].w * inv[h] + bb.w);
      *reinterpret_cast<float4*>(&out[(size_t)d * 256 + coff]) = o;
      float4 pw = *reinterpret_cast<const float4*>(&pool_w[coff]);
      sd += o.x * pw.x + o.y * pw.y + o.z * pw.z + o.w * pw.w;
    }
#pragma unroll
    for (int off = 1; off <= 8; off <<= 1) sd += __shfl_xor(sd, off);
    if (l16 == 0) score[d] = sd * inv_norm[0];
    return;
  }

  // ---- fallback: full wave per node, 4 nodes sequentially (dim <= 64) ----
  for (int pp = 0; pp < 4; pp++) {
    const int dd = order[ibase + pp];
    const int degp = min(cursor[dd], 63);
    const int dimp = degp + 1;
    const float4 add4 = *reinterpret_cast<const float4*>(&a_d[(size_t)dd * 4]);
    const bool has = lane < dimp;
    int s = (lane < degp) ? csr[(size_t)dd * 64 + lane] : dd;
    float4 as4 = *reinterpret_cast<const float4*>(&a_s[(size_t)s * 4]);
    float l0 = leakyrelu(as4.x + add4.x);
    float l1 = leakyrelu(as4.y + add4.y);
    float l2 = leakyrelu(as4.z + add4.z);
    float l3 = leakyrelu(as4.w + add4.w);
    float m0 = has ? l0 : -1e30f, m1 = has ? l1 : -1e30f;
    float m2 = has ? l2 : -1e30f, m3 = has ? l3 : -1e30f;
#pragma unroll
    for (int off = 1; off <= 32; off <<= 1) {
      m0 = fmaxf(m0, __shfl_xor(m0, off));
      m1 = fmaxf(m1, __shfl_xor(m1, off));
      m2 = fmaxf(m2, __shfl_xor(m2, off));
      m3 = fmaxf(m3, __shfl_xor(m3, off));
    }
    float e0 = has ? __expf(l0 - m0) : 0.f;
    float e1 = has ? __expf(l1 - m1) : 0.f;
    float e2 = has ? __expf(l2 - m2) : 0.f;
    float e3 = has ? __expf(l3 - m3) : 0.f;
    float dn0 = e0, dn1 = e1, dn2 = e2, dn3 = e3;
#pragma unroll
    for (int off = 1; off <= 32; off <<= 1) {
      dn0 += __shfl_xor(dn0, off);
      dn1 += __shfl_xor(dn1, off);
      dn2 += __shfl_xor(dn2, off);
      dn3 += __shfl_xor(dn3, off);
    }
    float4 acc0 = {0,0,0,0}, acc1 = {0,0,0,0}, acc2 = {0,0,0,0}, acc3 = {0,0,0,0};
    for (int base = 0; base < dimp; base += 4) {
      int t = base + p;
      int tc = (t < dimp) ? t : 0;
      int st = __shfl(s, tc);
      float c0 = __shfl(e0, tc), c1 = __shfl(e1, tc);
      float c2 = __shfl(e2, tc), c3 = __shfl(e3, tc);
      if (t < dimp) {
        const float4* hp = reinterpret_cast<const float4*>(&hW[(size_t)st * 256]) + l16;
        acc0 = f4fma(hp[0],  c0, acc0);
        acc1 = f4fma(hp[16], c1, acc1);
        acc2 = f4fma(hp[32], c2, acc2);
        acc3 = f4fma(hp[48], c3, acc3);
      }
    }
    acc0 = xgrp_sum(acc0); acc1 = xgrp_sum(acc1);
    acc2 = xgrp_sum(acc2); acc3 = xgrp_sum(acc3);
    const float inv0 = 1.f / (dn0 + 1e-16f), inv1 = 1.f / (dn1 + 1e-16f);
    const float inv2 = 1.f / (dn2 + 1e-16f), inv3 = 1.f / (dn3 + 1e-16f);
    float4 vb = (p == 0) ? acc0 : (p == 1) ? acc1 : (p == 2) ? acc2 : acc3;
    float invg = (p == 0) ? inv0 : (p == 1) ? inv1 : (p == 2) ? inv2 : inv3;
    const int coff = p * 64 + l16 * 4;
    float4 bb = *reinterpret_cast<const float4*>(&bias[coff]);
    float4 o;
    o.x = eluf(vb.x * invg + bb.x);
    o.y = eluf(vb.y * invg + bb.y);
    o.z = eluf(vb.z * invg + bb.z);
    o.w = eluf(vb.w * invg + bb.w);
    *reinterpret_cast<float4*>(&out[(size_t)dd * 256 + coff]) = o;
    float4 pw = *reinterpret_cast<const float4*>(&pool_w[coff]);
    float sd = o.x * pw.x + o.y * pw.y + o.z * pw.z + o.w * pw.w;
#pragma unroll
    for (int off = 1; off <= 32; off <<= 1) sd += __shfl_xor(sd, off);
    if (lane == 0) score[dd] = sd * inv_norm[0];
  }
}

// ---------------- per-graph bitonic top-k sort ----------------
__global__ __launch_bounds__(1024) void topk_sort(const float* __restrict__ score,
                                                  int npg, int k,
                                                  int* __restrict__ perm,
                                                  int* __restrict__ newid) {
  __shared__ float sv[2048];
  __shared__ int si[2048];
  int g = blockIdx.x;
  for (int i = threadIdx.x; i < npg; i += blockDim.x) {
    sv[i] = score[(size_t)g * npg + i];
    si[i] = i;
  }
  __syncthreads();
  for (int size = 2; size <= npg; size <<= 1) {
    for (int stride = size >> 1; stride > 0; stride >>= 1) {
      for (int i = threadIdx.x; i < npg; i += blockDim.x) {
        int j = i ^ stride;
        if (j > i) {
          bool desc = ((i & size) == 0);
          float vi = sv[i], vj = sv[j];
          int ii = si[i], ij = si[j];
          bool i_before_j = (vi > vj) || (vi == vj && ii < ij);
          bool doswap = desc ? !i_before_j : i_before_j;
          if (doswap) { sv[i] = vj; sv[j] = vi; si[i] = ij; si[j] = ii; }
        }
      }
      __syncthreads();
    }
  }
  for (int j = threadIdx.x; j < k; j += blockDim.x) {
    int node = g * npg + si[j];
    perm[g * k + j] = node;
    if (newid) newid[node] = g * k + j;
  }
}

// ------- pooled gather + gate dot; emits hi/lo bf16 slabs for next GEMM -----
__global__ void gather_pool(const float* __restrict__ hx, const int* __restrict__ perm,
                            const float* __restrict__ score,
                            const float* __restrict__ gate_w, const float* __restrict__ gate_b,
                            unsigned short* __restrict__ xshi, unsigned short* __restrict__ xslo,
                            float* __restrict__ gate, int nrows, int bpgl) {
  int j = swz_block(blockIdx.x, bpgl) * 4 + (threadIdx.x >> 6);
  int lane = threadIdx.x & 63;
  if (j >= nrows) return;
  int node = perm[j];
  float tsc = tanhf(score[node]);
  float4 v = reinterpret_cast<const float4*>(&hx[(size_t)node * 256])[lane];
  v.x *= tsc; v.y *= tsc; v.z *= tsc; v.w *= tsc;
  ushort4 h4, l4;
  h4.x = f2bf(v.x); l4.x = f2bf(v.x - bf2f(h4.x));
  h4.y = f2bf(v.y); l4.y = f2bf(v.y - bf2f(h4.y));
  h4.z = f2bf(v.z); l4.z = f2bf(v.z - bf2f(h4.z));
  h4.w = f2bf(v.w); l4.w = f2bf(v.w - bf2f(h4.w));
  *reinterpret_cast<ushort4*>(&xshi[(size_t)j * 256 + lane * 4]) = h4;
  *reinterpret_cast<ushort4*>(&xslo[(size_t)j * 256 + lane * 4]) = l4;
  float4 gw = reinterpret_cast<const float4*>(gate_w)[lane];
  float gd = v.x * gw.x + v.y * gw.y + v.z * gw.z + v.w * gw.w;
#pragma unroll
  for (int off = 32; off >= 1; off >>= 1) gd += __shfl_xor(gd, off);
  if (lane == 0) gate[j] = gd + gate_b[0];
}

// ---------------- attention pooling, 3-stage ----------------
__global__ __launch_bounds__(256) void gate_softmax(float* __restrict__ gate, int npg) {
  int g = blockIdx.x, tid = threadIdx.x;
  __shared__ float red[256];
  size_t base = (size_t)g * npg;
  float m = -1e30f;
  for (int i = tid; i < npg; i += 256) m = fmaxf(m, gate[base + i]);
  red[tid] = m;
  __syncthreads();
  for (int s = 128; s >= 1; s >>= 1) {
    if (tid < s) red[tid] = fmaxf(red[tid], red[tid + s]);
    __syncthreads();
  }
  m = red[0];
  __syncthreads();
  float ss = 0.f;
  for (int i = tid; i < npg; i += 256) ss += __expf(gate[base + i] - m);
  red[tid] = ss;
  __syncthreads();
  for (int s = 128; s >= 1; s >>= 1) {
    if (tid < s) red[tid] += red[tid + s];
    __syncthreads();
  }
  float inv = 1.f / red[0];
  __syncthreads();
  for (int i = tid; i < npg; i += 256) gate[base + i] = __expf(gate[base + i] - m) * inv;
}

__global__ __launch_bounds__(256) void attpool_sum(const unsigned short* __restrict__ xhi,
                                                   const unsigned short* __restrict__ xlo,
                                                   const float* __restrict__ wts,
                                                   float* __restrict__ partials,
                                                   int npg, int nch) {
  int g = blockIdx.x / nch, sub = blockIdx.x % nch;
  int c = threadIdx.x;
  size_t r0 = (size_t)g * npg + sub * 32;
  float a = 0.f;
#pragma unroll 8
  for (int i = 0; i < 32; i++) {
    float v = bf2f(xhi[(r0 + i) * 256 + c]) + bf2f(xlo[(r0 + i) * 256 + c]);
    a += wts[r0 + i] * v;
  }
  partials[(size_t)blockIdx.x * 256 + c] = a;
}

__global__ __launch_bounds__(256) void attpool_reduce(const float* __restrict__ partials,
                                                      float* __restrict__ out,
                                                      int nch, int acc_flag) {
  int g = blockIdx.x, c = threadIdx.x;
  float a = 0.f;
  for (int s = 0; s < nch; s++) a += partials[((size_t)g * nch + s) * 256 + c];
  if (acc_flag) out[g * 256 + c] += a;
  else out[g * 256 + c] = a;
}

}  // namespace

extern "C" void kernel_launch(void* const* d_in, const int* in_sizes, int n_in,
                              void* d_out, int out_size, void* d_ws, size_t ws_size,
                              hipStream_t stream) {
  (void)in_sizes; (void)n_in; (void)out_size; (void)ws_size;
  const float* x       = (const float*)d_in[0];
  const int*   ei      = (const int*)d_in[1];
  const float* lin0_w  = (const float*)d_in[2];
  const float* lin0_b  = (const float*)d_in[3];
  const float* gat0_W  = (const float*)d_in[4];
  const float* gat0_as = (const float*)d_in[5];
  const float* gat0_ad = (const float*)d_in[6];
  const float* gat0_b  = (const float*)d_in[7];
  const float* pool0_w = (const float*)d_in[8];
  const float* gat1_W  = (const float*)d_in[9];
  const float* gat1_as = (const float*)d_in[10];
  const float* gat1_ad = (const float*)d_in[11];
  const float* gat1_b  = (const float*)d_in[12];
  const float* pool1_w = (const float*)d_in[13];
  const float* gate_w  = (const float*)d_in[14];
  const float* gate_b  = (const float*)d_in[15];
  float* out = (float*)d_out;
  const int* srcp = ei;
  const int* dstp = ei + NE;

  char* wsb = (char*)d_ws;
  size_t cur = 0;
  auto alloc = [&](size_t bytes) {
    void* p = wsb + cur;
    cur = (cur + bytes + 255) & ~(size_t)255;
    return p;
  };
  char* regA = (char*)alloc((size_t)NN0 * 256 * 4);        // out0 -> {hW1,out1}
  char* regB = (char*)alloc((size_t)NN0 * 256 * 4);        // hW0 -> xs1hi/lo
  char* regD = (char*)alloc((size_t)NN0 * KP * 2 * 2);     // xhi/xlo -> xs0hi/lo
  float* a_s     = (float*)alloc((size_t)NN0 * 4 * 4);
  float* a_d     = (float*)alloc((size_t)NN0 * 4 * 4);
  int*   cursor  = (int*)alloc((size_t)NN0 * 4);
  int*   csr     = (int*)alloc((size_t)NN0 * 64 * 4);
  float* score   = (float*)alloc((size_t)NN0 * 4);
  int*   newid   = (int*)alloc((size_t)NN0 * 4);
  int*   perm    = (int*)alloc((size_t)NB * 1024 * 4);
  float* gateb   = (float*)alloc((size_t)32768 * 4);
  float* partials= (float*)alloc((size_t)NB * 32 * 256 * 4);
  int*   order   = (int*)alloc((size_t)NN0 * 4);
  int*   bins    = (int*)alloc((size_t)NB * 72 * 4);
  float* norms   = (float*)alloc(2 * 4);
  unsigned short* whi0 = (unsigned short*)alloc((size_t)5 * 8192 * 2);
  unsigned short* wlo0 = (unsigned short*)alloc((size_t)5 * 8192 * 2);
  unsigned short* whi1 = (unsigned short*)alloc((size_t)8 * 8192 * 2);
  unsigned short* wlo1 = (unsigned short*)alloc((size_t)8 * 8192 * 2);
  unsigned short* whi2 = (unsigned short*)alloc((size_t)8 * 8192 * 2);
  unsigned short* wlo2 = (unsigned short*)alloc((size_t)8 * 8192 * 2);

  unsigned short* xhi = (unsigned short*)regD;
  unsigned short* xlo = xhi + (size_t)NN0 * KP;
  float* hW0  = (float*)regB;
  float* out0 = (float*)regA;
  unsigned short* xs0hi = (unsigned short*)regD;
  unsigned short* xs0lo = xs0hi + (size_t)32768 * 256;
  float* hW1  = (float*)regA;
  float* out1 = (float*)(regA + (size_t)32768 * 256 * 4);
  unsigned short* xs1hi = (unsigned short*)regB;
  unsigned short* xs1lo = xs1hi + (size_t)16384 * 256;

  pack_w<<<(5 * 8192 + 255) / 256, 256, 0, stream>>>(lin0_w, FIN, 5, whi0, wlo0);
  pack_w<<<(8 * 8192 + 255) / 256, 256, 0, stream>>>(gat0_W, 256, 8, whi1, wlo1);
  pack_w<<<(8 * 8192 + 255) / 256, 256, 0, stream>>>(gat1_W, 256, 8, whi2, wlo2);
  pack_x<<<(NN0 * KP + 255) / 256, 256, 0, stream>>>(x, xhi, xlo);
  pool_norms<<<1, 64, 0, stream>>>(pool0_w, pool1_w, norms);

  // ---- GAT0 prep: CSR + degree-sorted order ----
  hipMemsetAsync(cursor, 0, (size_t)NN0 * 4, stream);
  scatter0<<<NE / 256, 256, 0, stream>>>(srcp, dstp, cursor, csr);
  hipMemsetAsync(bins, 0, (size_t)NB * 72 * 4, stream);
  hist_dim<<<NN0 / 256, 256, 0, stream>>>(cursor, bins, NN0, 11);
  scan_bins<<<NB, 64, 0, stream>>>(bins);
  scatter_ord<<<NN0 / 256, 256, 0, stream>>>(cursor, bins, order, NN0, 11);

  // ---- fused lin0+GAT0 GEMM -> hW0 + a_s/a_d ----
  gemm_fused<5><<<NN0 / 64, 256, 0, stream>>>(
      xhi, xlo, KP, whi0, wlo0, lin0_b, whi1, wlo1, hW0,
      gat0_as, gat0_ad, a_s, a_d);

  gat_node16<<<NN0 / 16, 256, 0, stream>>>(cursor, csr, order, a_s, a_d, hW0,
                                           gat0_b, pool0_w, norms, out0, score, 7);

  // ---- pool0: top-1024 of 2048 per graph ----
  hipMemsetAsync(newid, 0xFF, (size_t)NN0 * 4, stream);
  topk_sort<<<NB, 1024, 0, stream>>>(score, 2048, 1024, perm, newid);
  gather_pool<<<32768 / 4, 256, 0, stream>>>(out0, perm, score, gate_w, gate_b,
                                             xs0hi, xs0lo, gateb, 32768, 8);
  gate_softmax<<<NB, 256, 0, stream>>>(gateb, 1024);
  attpool_sum<<<NB * 32, 256, 0, stream>>>(xs0hi, xs0lo, gateb, partials, 1024, 32);
  attpool_reduce<<<NB, 256, 0, stream>>>(partials, out, 32, 0);

  // ---- GAT1 prep: fused remap+scatter + degree-sorted order ----
  hipMemsetAsync(cursor, 0, (size_t)32768 * 4, stream);
  scatter1<<<NE / 256, 256, 0, stream>>>(srcp, dstp, newid, cursor, csr);
  hipMemsetAsync(bins, 0, (size_t)NB * 72 * 4, stream);
  hist_dim<<<32768 / 256, 256, 0, stream>>>(cursor, bins, 32768, 10);
  scan_bins<<<NB, 64, 0, stream>>>(bins);
  scatter_ord<<<32768 / 256, 256, 0, stream>>>(cursor, bins, order, 32768, 10);

  // ---- GAT1 GEMM + aggregation ----
  gemm_att<8><<<32768 / 64, 256, 0, stream>>>(
      xs0hi, xs0lo, 256, whi2, wlo2, hW1, gat1_as, gat1_ad, a_s, a_d);
  gat_node16<<<32768 / 16, 256, 0, stream>>>(cursor, csr, order, a_s, a_d, hW1,
                                             gat1_b, pool1_w, norms + 1, out1, score, 6);

  // ---- pool1: top-512 of 1024 per graph ----
  topk_sort<<<NB, 1024, 0, stream>>>(score, 1024, 512, perm, nullptr);
  gather_pool<<<16384 / 4, 256, 0, stream>>>(out1, perm, score, gate_w, gate_b,
                                             xs1hi, xs1lo, gateb, 16384, 7);
  gate_softmax<<<NB, 256, 0, stream>>>(gateb, 512);
  attpool_sum<<<NB * 16, 256, 0, stream>>>(xs1hi, xs1lo, gateb, partials, 512, 16);
  attpool_reduce<<<NB, 256, 0, stream>>>(partials, out, 16, 1);
}

// Round 9
// 357.924 us; speedup vs baseline: 1.0072x; 1.0072x over previous
//
#include <hip/hip_runtime.h>
#include <cmath>

namespace {

constexpr int NN0 = 65536;   // nodes stage 0
constexpr int NB  = 32;      // graphs
constexpr int NE  = 524288;  // edges
constexpr int FIN = 129;
constexpr int KP  = 160;     // padded K for lin0 (5 k-tiles of 32)

typedef short bf16x8 __attribute__((ext_vector_type(8)));
typedef float f32x4 __attribute__((ext_vector_type(4)));

__device__ inline float leakyrelu(float z) { return z > 0.f ? z : 0.2f * z; }
__device__ inline float eluf(float z) { return z > 0.f ? z : expm1f(z); }

__device__ inline unsigned short f2bf(float x) {
  union { float f; unsigned int u; } v; v.f = x;
  unsigned int r = v.u + 0x7fffu + ((v.u >> 16) & 1u);
  return (unsigned short)(r >> 16);
}
__device__ inline float bf2f(unsigned short h) {
  union { unsigned int u; float f; } v; v.u = ((unsigned int)h) << 16;
  return v.f;
}

__device__ inline float4 f4fma(float4 a, float c, float4 acc) {
  acc.x += a.x * c; acc.y += a.y * c; acc.z += a.z * c; acc.w += a.w * c;
  return acc;
}
__device__ inline float4 xgrp_sum(float4 v) {
#pragma unroll
  for (int off = 16; off <= 32; off <<= 1) {
    v.x += __shfl_xor(v.x, off);
    v.y += __shfl_xor(v.y, off);
    v.z += __shfl_xor(v.z, off);
    v.w += __shfl_xor(v.w, off);
  }
  return v;
}

// XCD-aware block swizzle (bijective; NB%8==0)
__device__ inline int swz_block(int bid, int bpgl) {
  int x = bid & 7;
  int local = bid >> 3;
  int g = x + ((local >> bpgl) << 3);
  return (g << bpgl) + (local & ((1 << bpgl) - 1));
}

__device__ __forceinline__ void gload_lds16(const unsigned short* g, unsigned short* l) {
  __builtin_amdgcn_global_load_lds((const unsigned int*)g, (unsigned int*)l, 16, 0, 0);
}

// ---------------- pack input x -> hi/lo bf16, K padded 129->160 -------------
__global__ void pack_x(const float* __restrict__ x,
                       unsigned short* __restrict__ xhi, unsigned short* __restrict__ xlo) {
  int idx = blockIdx.x * 256 + threadIdx.x;
  if (idx >= NN0 * KP) return;
  int row = idx / KP, c = idx - row * KP;
  float v = (c < FIN) ? x[(size_t)row * FIN + c] : 0.f;
  unsigned short h = f2bf(v);
  xhi[idx] = h;
  xlo[idx] = f2bf(v - bf2f(h));
}

// ---------------- W fragment pack: fp32 [K][256] -> hi/lo bf16 fragments ----
__global__ void pack_w(const float* __restrict__ W, int Kreal, int KT,
                       unsigned short* __restrict__ hi, unsigned short* __restrict__ lo) {
  int idx = blockIdx.x * blockDim.x + threadIdx.x;
  if (idx >= KT * 8192) return;
  int j = idx & 7;
  int lane = (idx >> 3) & 63;
  int ct = (idx >> 9) & 15;
  int kt = idx >> 13;
  int k = kt * 32 + ((lane >> 4) << 3) + j;
  int c = ct * 16 + (lane & 15);
  float v = (k < Kreal) ? W[(size_t)k * 256 + c] : 0.f;
  unsigned short h = f2bf(v);
  hi[idx] = h;
  lo[idx] = f2bf(v - bf2f(h));
}

// ---------------- pool-weight inverse norms ----------------
__global__ void pool_norms(const float* __restrict__ w0, const float* __restrict__ w1,
                           float* __restrict__ norms) {
  int lane = threadIdx.x;
  float a0 = 0.f, a1 = 0.f;
#pragma unroll
  for (int j = lane; j < 256; j += 64) {
    float v0 = w0[j]; a0 += v0 * v0;
    float v1 = w1[j]; a1 += v1 * v1;
  }
#pragma unroll
  for (int off = 32; off >= 1; off >>= 1) {
    a0 += __shfl_xor(a0, off);
    a1 += __shfl_xor(a1, off);
  }
  if (lane == 0) {
    norms[0] = 1.f / (sqrtf(a0) + 1e-16f);
    norms[1] = 1.f / (sqrtf(a1) + 1e-16f);
  }
}

// ---------------- split-bf16 3-pass MFMA GEMM, BM=64 x BN=256 ----------------
template <int KT, bool RELUBIAS, bool ATT>
__global__ __launch_bounds__(256, 2) void gemm_mfma(
    const unsigned short* __restrict__ Xhi, const unsigned short* __restrict__ Xlo,
    int ldx,
    const unsigned short* __restrict__ Bhi, const unsigned short* __restrict__ Blo,
    const float* __restrict__ bias,
    float* __restrict__ Out,
    unsigned short* __restrict__ OutHi, unsigned short* __restrict__ OutLo,
    const float* __restrict__ attsrc, const float* __restrict__ attdst,
    float* __restrict__ a_s, float* __restrict__ a_d) {
  __shared__ __align__(16) unsigned short As[2][2][64][32];  // 16 KB
  const int tid = threadIdx.x;
  const int lane = tid & 63;
  const int w = tid >> 6;
  const int row0 = blockIdx.x * 64;
  const int l15 = lane & 15, q = lane >> 4;
  const int srow = w * 16 + (lane >> 2);
  const int skc = (lane & 3) * 8;

  auto stage = [&](int nb, int kt) {
    const size_t goff = (size_t)(row0 + srow) * ldx + kt * 32 + skc;
    gload_lds16(Xhi + goff, &As[nb][0][w * 16][0]);
    gload_lds16(Xlo + goff, &As[nb][1][w * 16][0]);
  };

  f32x4 acc[4][4];
#pragma unroll
  for (int mf = 0; mf < 4; mf++)
#pragma unroll
    for (int nf = 0; nf < 4; nf++) acc[mf][nf] = (f32x4)(0.f);

  stage(0, 0);
  __syncthreads();

#pragma unroll
  for (int kt = 0; kt < KT; ++kt) {
    const int nb = kt & 1;
    if (kt + 1 < KT) stage(nb ^ 1, kt + 1);
    bf16x8 bh[4], bl[4];
#pragma unroll
    for (int nf = 0; nf < 4; nf++) {
      const int ct = w * 4 + nf;
      const size_t bbase = ((size_t)((kt * 16 + ct) * 64 + lane)) << 3;
      bh[nf] = *reinterpret_cast<const bf16x8*>(Bhi + bbase);
      bl[nf] = *reinterpret_cast<const bf16x8*>(Blo + bbase);
    }
    bf16x8 ah[4], al[4];
#pragma unroll
    for (int mf = 0; mf < 4; mf++) {
      const int ar = mf * 16 + l15;
      ah[mf] = *reinterpret_cast<const bf16x8*>(&As[nb][0][ar][q * 8]);
      al[mf] = *reinterpret_cast<const bf16x8*>(&As[nb][1][ar][q * 8]);
    }
#pragma unroll
    for (int mf = 0; mf < 4; mf++)
#pragma unroll
      for (int nf = 0; nf < 4; nf++) {
        acc[mf][nf] = __builtin_amdgcn_mfma_f32_16x16x32_bf16(ah[mf], bh[nf], acc[mf][nf], 0, 0, 0);
        acc[mf][nf] = __builtin_amdgcn_mfma_f32_16x16x32_bf16(ah[mf], bl[nf], acc[mf][nf], 0, 0, 0);
        acc[mf][nf] = __builtin_amdgcn_mfma_f32_16x16x32_bf16(al[mf], bh[nf], acc[mf][nf], 0, 0, 0);
      }
    __syncthreads();
  }

#pragma unroll
  for (int mf = 0; mf < 4; mf++) {
    const int rowb = row0 + mf * 16 + q * 4;
#pragma unroll
    for (int r = 0; r < 4; r++) {
#pragma unroll
      for (int nf = 0; nf < 4; nf++) {
        float v = acc[mf][nf][r];
        const int col = w * 64 + nf * 16 + l15;
        if constexpr (RELUBIAS) {
          v += bias[col];
          v = fmaxf(v, 0.f);
          unsigned short h = f2bf(v);
          OutHi[(size_t)(rowb + r) * 256 + col] = h;
          OutLo[(size_t)(rowb + r) * 256 + col] = f2bf(v - bf2f(h));
        } else {
          Out[(size_t)(rowb + r) * 256 + col] = v;
        }
      }
    }
  }
  if constexpr (ATT) {
    const int head = w;
    float sv[4], dv[4];
#pragma unroll
    for (int nf = 0; nf < 4; nf++) {
      sv[nf] = attsrc[head * 64 + nf * 16 + l15];
      dv[nf] = attdst[head * 64 + nf * 16 + l15];
    }
#pragma unroll
    for (int mf = 0; mf < 4; mf++) {
#pragma unroll
      for (int r = 0; r < 4; r++) {
        float ps = 0.f, pd = 0.f;
#pragma unroll
        for (int nf = 0; nf < 4; nf++) {
          ps += acc[mf][nf][r] * sv[nf];
          pd += acc[mf][nf][r] * dv[nf];
        }
#pragma unroll
        for (int off = 8; off >= 1; off >>= 1) {
          ps += __shfl_xor(ps, off);
          pd += __shfl_xor(pd, off);
        }
        if (l15 == 0) {
          const int row = row0 + mf * 16 + q * 4 + r;
          a_s[(size_t)row * 4 + head] = ps;
          a_d[(size_t)row * 4 + head] = pd;
        }
      }
    }
  }
}

// ---------------- stride-64 CSR scatter ----------------
__global__ void scatter0(const int* __restrict__ src, const int* __restrict__ dst,
                         int* __restrict__ cursor, int* __restrict__ csr) {
  int e = blockIdx.x * blockDim.x + threadIdx.x;
  if (e >= NE) return;
  int d = dst[e];
  int pos = atomicAdd(&cursor[d], 1);
  if (pos < 64) csr[(size_t)d * 64 + pos] = src[e];
}

__global__ void scatter1(const int* __restrict__ src, const int* __restrict__ dst,
                         const int* __restrict__ newid,
                         int* __restrict__ cursor, int* __restrict__ csr) {
  int e = blockIdx.x * blockDim.x + threadIdx.x;
  if (e >= NE) return;
  int s = newid[src[e]], d = newid[dst[e]];
  if (s < 0 || d < 0) return;
  int pos = atomicAdd(&cursor[d], 1);
  if (pos < 64) csr[(size_t)d * 64 + pos] = s;
}

// --------- per-dest-node GAT: 8 nodes/wave (2 per 16-lane group) ------------
// Group p handles nodes A=ibase+p, B=ibase+4+p; doubles outstanding loads.
__global__ __launch_bounds__(256) void gat_node16(
    const int* __restrict__ cursor, const int* __restrict__ csr,
    const float* __restrict__ a_s, const float* __restrict__ a_d,
    const float* __restrict__ hW, const float* __restrict__ bias,
    const float* __restrict__ pool_w, const float* __restrict__ inv_norm,
    float* __restrict__ out, float* __restrict__ score, int bpgl) {
  const int lane = threadIdx.x & 63;
  const int wv = threadIdx.x >> 6;
  const int ibase = swz_block(blockIdx.x, bpgl) * 32 + wv * 8;
  const int p = lane >> 4, l16 = lane & 15;

  const int dA = ibase + p, dB = ibase + 4 + p;
  const int degA = min(cursor[dA], 63), dimA = degA + 1;
  const int degB = min(cursor[dB], 63), dimB = degB + 1;

  if (__all(dimA <= 16 && dimB <= 16)) {
    const float4 adA = *reinterpret_cast<const float4*>(&a_d[(size_t)dA * 4]);
    const float4 adB = *reinterpret_cast<const float4*>(&a_d[(size_t)dB * 4]);
    const bool hA = l16 < dimA, hB = l16 < dimB;
    int sA = (l16 < degA) ? csr[(size_t)dA * 64 + l16] : dA;
    int sB = (l16 < degB) ? csr[(size_t)dB * 64 + l16] : dB;
    float4 asA = *reinterpret_cast<const float4*>(&a_s[(size_t)sA * 4]);
    float4 asB = *reinterpret_cast<const float4*>(&a_s[(size_t)sB * 4]);
    float lA0 = leakyrelu(asA.x + adA.x), lA1 = leakyrelu(asA.y + adA.y);
    float lA2 = leakyrelu(asA.z + adA.z), lA3 = leakyrelu(asA.w + adA.w);
    float lB0 = leakyrelu(asB.x + adB.x), lB1 = leakyrelu(asB.y + adB.y);
    float lB2 = leakyrelu(asB.z + adB.z), lB3 = leakyrelu(asB.w + adB.w);
    float mA0 = hA ? lA0 : -1e30f, mA1 = hA ? lA1 : -1e30f;
    float mA2 = hA ? lA2 : -1e30f, mA3 = hA ? lA3 : -1e30f;
    float mB0 = hB ? lB0 : -1e30f, mB1 = hB ? lB1 : -1e30f;
    float mB2 = hB ? lB2 : -1e30f, mB3 = hB ? lB3 : -1e30f;
#pragma unroll
    for (int off = 1; off <= 8; off <<= 1) {
      mA0 = fmaxf(mA0, __shfl_xor(mA0, off));
      mA1 = fmaxf(mA1, __shfl_xor(mA1, off));
      mA2 = fmaxf(mA2, __shfl_xor(mA2, off));
      mA3 = fmaxf(mA3, __shfl_xor(mA3, off));
      mB0 = fmaxf(mB0, __shfl_xor(mB0, off));
      mB1 = fmaxf(mB1, __shfl_xor(mB1, off));
      mB2 = fmaxf(mB2, __shfl_xor(mB2, off));
      mB3 = fmaxf(mB3, __shfl_xor(mB3, off));
    }
    float eA0 = hA ? __expf(lA0 - mA0) : 0.f;
    float eA1 = hA ? __expf(lA1 - mA1) : 0.f;
    float eA2 = hA ? __expf(lA2 - mA2) : 0.f;
    float eA3 = hA ? __expf(lA3 - mA3) : 0.f;
    float eB0 = hB ? __expf(lB0 - mB0) : 0.f;
    float eB1 = hB ? __expf(lB1 - mB1) : 0.f;
    float eB2 = hB ? __expf(lB2 - mB2) : 0.f;
    float eB3 = hB ? __expf(lB3 - mB3) : 0.f;
    float nA0 = eA0, nA1 = eA1, nA2 = eA2, nA3 = eA3;
    float nB0 = eB0, nB1 = eB1, nB2 = eB2, nB3 = eB3;
#pragma unroll
    for (int off = 1; off <= 8; off <<= 1) {
      nA0 += __shfl_xor(nA0, off);
      nA1 += __shfl_xor(nA1, off);
      nA2 += __shfl_xor(nA2, off);
      nA3 += __shfl_xor(nA3, off);
      nB0 += __shfl_xor(nB0, off);
      nB1 += __shfl_xor(nB1, off);
      nB2 += __shfl_xor(nB2, off);
      nB3 += __shfl_xor(nB3, off);
    }
    int dmax = max(dimA, dimB);
    dmax = max(dmax, __shfl_xor(dmax, 16));
    dmax = max(dmax, __shfl_xor(dmax, 32));
    float4 accA[4], accB[4];
#pragma unroll
    for (int h = 0; h < 4; h++) {
      accA[h] = float4{0.f, 0.f, 0.f, 0.f};
      accB[h] = float4{0.f, 0.f, 0.f, 0.f};
    }
#pragma unroll 2
    for (int t = 0; t < dmax; t++) {
      const int idx = p * 16 + t;
      int stA = __shfl(sA, idx), stB = __shfl(sB, idx);
      float cA0 = __shfl(eA0, idx), cA1 = __shfl(eA1, idx);
      float cA2 = __shfl(eA2, idx), cA3 = __shfl(eA3, idx);
      float cB0 = __shfl(eB0, idx), cB1 = __shfl(eB1, idx);
      float cB2 = __shfl(eB2, idx), cB3 = __shfl(eB3, idx);
      if (t < dimA) {
        const float4* hp = reinterpret_cast<const float4*>(&hW[(size_t)stA * 256]) + l16;
        accA[0] = f4fma(hp[0],  cA0, accA[0]);
        accA[1] = f4fma(hp[16], cA1, accA[1]);
        accA[2] = f4fma(hp[32], cA2, accA[2]);
        accA[3] = f4fma(hp[48], cA3, accA[3]);
      }
      if (t < dimB) {
        const float4* hp = reinterpret_cast<const float4*>(&hW[(size_t)stB * 256]) + l16;
        accB[0] = f4fma(hp[0],  cB0, accB[0]);
        accB[1] = f4fma(hp[16], cB1, accB[1]);
        accB[2] = f4fma(hp[32], cB2, accB[2]);
        accB[3] = f4fma(hp[48], cB3, accB[3]);
      }
    }
    const float invA[4] = {1.f / (nA0 + 1e-16f), 1.f / (nA1 + 1e-16f),
                           1.f / (nA2 + 1e-16f), 1.f / (nA3 + 1e-16f)};
    const float invB[4] = {1.f / (nB0 + 1e-16f), 1.f / (nB1 + 1e-16f),
                           1.f / (nB2 + 1e-16f), 1.f / (nB3 + 1e-16f)};
    float sdA = 0.f, sdB = 0.f;
#pragma unroll
    for (int h = 0; h < 4; h++) {
      const int coff = h * 64 + l16 * 4;
      float4 bb = *reinterpret_cast<const float4*>(&bias[coff]);
      float4 pw = *reinterpret_cast<const float4*>(&pool_w[coff]);
      float4 oA, oB;
      oA.x = eluf(accA[h].x * invA[h] + bb.x);
      oA.y = eluf(accA[h].y * invA[h] + bb.y);
      oA.z = eluf(accA[h].z * invA[h] + bb.z);
      oA.w = eluf(accA[h].w * invA[h] + bb.w);
      oB.x = eluf(accB[h].x * invB[h] + bb.x);
      oB.y = eluf(accB[h].y * invB[h] + bb.y);
      oB.z = eluf(accB[h].z * invB[h] + bb.z);
      oB.w = eluf(accB[h].w * invB[h] + bb.w);
      *reinterpret_cast<float4*>(&out[(size_t)dA * 256 + coff]) = oA;
      *reinterpret_cast<float4*>(&out[(size_t)dB * 256 + coff]) = oB;
      sdA += oA.x * pw.x + oA.y * pw.y + oA.z * pw.z + oA.w * pw.w;
      sdB += oB.x * pw.x + oB.y * pw.y + oB.z * pw.z + oB.w * pw.w;
    }
#pragma unroll
    for (int off = 1; off <= 8; off <<= 1) {
      sdA += __shfl_xor(sdA, off);
      sdB += __shfl_xor(sdB, off);
    }
    if (l16 == 0) {
      score[dA] = sdA * inv_norm[0];
      score[dB] = sdB * inv_norm[0];
    }
    return;
  }

  // ---- fallback: full wave per node, 8 nodes sequentially (dim <= 64) ----
  for (int pp = 0; pp < 8; pp++) {
    const int dd = ibase + pp;
    const int degp = min(cursor[dd], 63);
    const int dimp = degp + 1;
    const float4 add4 = *reinterpret_cast<const float4*>(&a_d[(size_t)dd * 4]);
    const bool has = lane < dimp;
    int s = (lane < degp) ? csr[(size_t)dd * 64 + lane] : dd;
    float4 as4 = *reinterpret_cast<const float4*>(&a_s[(size_t)s * 4]);
    float l0 = leakyrelu(as4.x + add4.x);
    float l1 = leakyrelu(as4.y + add4.y);
    float l2 = leakyrelu(as4.z + add4.z);
    float l3 = leakyrelu(as4.w + add4.w);
    float m0 = has ? l0 : -1e30f, m1 = has ? l1 : -1e30f;
    float m2 = has ? l2 : -1e30f, m3 = has ? l3 : -1e30f;
#pragma unroll
    for (int off = 1; off <= 32; off <<= 1) {
      m0 = fmaxf(m0, __shfl_xor(m0, off));
      m1 = fmaxf(m1, __shfl_xor(m1, off));
      m2 = fmaxf(m2, __shfl_xor(m2, off));
      m3 = fmaxf(m3, __shfl_xor(m3, off));
    }
    float e0 = has ? __expf(l0 - m0) : 0.f;
    float e1 = has ? __expf(l1 - m1) : 0.f;
    float e2 = has ? __expf(l2 - m2) : 0.f;
    float e3 = has ? __expf(l3 - m3) : 0.f;
    float dn0 = e0, dn1 = e1, dn2 = e2, dn3 = e3;
#pragma unroll
    for (int off = 1; off <= 32; off <<= 1) {
      dn0 += __shfl_xor(dn0, off);
      dn1 += __shfl_xor(dn1, off);
      dn2 += __shfl_xor(dn2, off);
      dn3 += __shfl_xor(dn3, off);
    }
    const int p4 = lane >> 4, l16b = lane & 15;
    float4 acc0 = {0,0,0,0}, acc1 = {0,0,0,0}, acc2 = {0,0,0,0}, acc3 = {0,0,0,0};
    for (int base = 0; base < dimp; base += 4) {
      int t = base + p4;
      int tc = (t < dimp) ? t : 0;
      int st = __shfl(s, tc);
      float c0 = __shfl(e0, tc), c1 = __shfl(e1, tc);
      float c2 = __shfl(e2, tc), c3 = __shfl(e3, tc);
      if (t < dimp) {
        const float4* hp = reinterpret_cast<const float4*>(&hW[(size_t)st * 256]) + l16b;
        acc0 = f4fma(hp[0],  c0, acc0);
        acc1 = f4fma(hp[16], c1, acc1);
        acc2 = f4fma(hp[32], c2, acc2);
        acc3 = f4fma(hp[48], c3, acc3);
      }
    }
    acc0 = xgrp_sum(acc0); acc1 = xgrp_sum(acc1);
    acc2 = xgrp_sum(acc2); acc3 = xgrp_sum(acc3);
    const float inv0 = 1.f / (dn0 + 1e-16f), inv1 = 1.f / (dn1 + 1e-16f);
    const float inv2 = 1.f / (dn2 + 1e-16f), inv3 = 1.f / (dn3 + 1e-16f);
    float4 vb = (p4 == 0) ? acc0 : (p4 == 1) ? acc1 : (p4 == 2) ? acc2 : acc3;
    float invg = (p4 == 0) ? inv0 : (p4 == 1) ? inv1 : (p4 == 2) ? inv2 : inv3;
    const int coff = p4 * 64 + l16b * 4;
    float4 bb = *reinterpret_cast<const float4*>(&bias[coff]);
    float4 o;
    o.x = eluf(vb.x * invg + bb.x);
    o.y = eluf(vb.y * invg + bb.y);
    o.z = eluf(vb.z * invg + bb.z);
    o.w = eluf(vb.w * invg + bb.w);
    *reinterpret_cast<float4*>(&out[(size_t)dd * 256 + coff]) = o;
    float4 pw = *reinterpret_cast<const float4*>(&pool_w[coff]);
    float sd = o.x * pw.x + o.y * pw.y + o.z * pw.z + o.w * pw.w;
#pragma unroll
    for (int off = 1; off <= 32; off <<= 1) sd += __shfl_xor(sd, off);
    if (lane == 0) score[dd] = sd * inv_norm[0];
  }
}

// ---------------- per-graph bitonic top-k sort ----------------
__global__ __launch_bounds__(1024) void topk_sort(const float* __restrict__ score,
                                                  int npg, int k,
                                                  int* __restrict__ perm,
                                                  int* __restrict__ newid) {
  __shared__ float sv[2048];
  __shared__ int si[2048];
  int g = blockIdx.x;
  for (int i = threadIdx.x; i < npg; i += blockDim.x) {
    sv[i] = score[(size_t)g * npg + i];
    si[i] = i;
  }
  __syncthreads();
  for (int size = 2; size <= npg; size <<= 1) {
    for (int stride = size >> 1; stride > 0; stride >>= 1) {
      for (int i = threadIdx.x; i < npg; i += blockDim.x) {
        int j = i ^ stride;
        if (j > i) {
          bool desc = ((i & size) == 0);
          float vi = sv[i], vj = sv[j];
          int ii = si[i], ij = si[j];
          bool i_before_j = (vi > vj) || (vi == vj && ii < ij);
          bool doswap = desc ? !i_before_j : i_before_j;
          if (doswap) { sv[i] = vj; sv[j] = vi; si[i] = ij; si[j] = ii; }
        }
      }
      __syncthreads();
    }
  }
  for (int j = threadIdx.x; j < k; j += blockDim.x) {
    int node = g * npg + si[j];
    perm[g * k + j] = node;
    if (newid) newid[node] = g * k + j;
  }
}

// ------- pooled gather + gate dot; emits hi/lo bf16 slabs for next GEMM -----
__global__ void gather_pool(const float* __restrict__ hx, const int* __restrict__ perm,
                            const float* __restrict__ score,
                            const float* __restrict__ gate_w, const float* __restrict__ gate_b,
                            unsigned short* __restrict__ xshi, unsigned short* __restrict__ xslo,
                            float* __restrict__ gate, int nrows, int bpgl) {
  int j = swz_block(blockIdx.x, bpgl) * 4 + (threadIdx.x >> 6);
  int lane = threadIdx.x & 63;
  if (j >= nrows) return;
  int node = perm[j];
  float tsc = tanhf(score[node]);
  float4 v = reinterpret_cast<const float4*>(&hx[(size_t)node * 256])[lane];
  v.x *= tsc; v.y *= tsc; v.z *= tsc; v.w *= tsc;
  ushort4 h4, l4;
  h4.x = f2bf(v.x); l4.x = f2bf(v.x - bf2f(h4.x));
  h4.y = f2bf(v.y); l4.y = f2bf(v.y - bf2f(h4.y));
  h4.z = f2bf(v.z); l4.z = f2bf(v.z - bf2f(h4.z));
  h4.w = f2bf(v.w); l4.w = f2bf(v.w - bf2f(h4.w));
  *reinterpret_cast<ushort4*>(&xshi[(size_t)j * 256 + lane * 4]) = h4;
  *reinterpret_cast<ushort4*>(&xslo[(size_t)j * 256 + lane * 4]) = l4;
  float4 gw = reinterpret_cast<const float4*>(gate_w)[lane];
  float gd = v.x * gw.x + v.y * gw.y + v.z * gw.z + v.w * gw.w;
#pragma unroll
  for (int off = 32; off >= 1; off >>= 1) gd += __shfl_xor(gd, off);
  if (lane == 0) gate[j] = gd + gate_b[0];
}

// ---------------- attention pooling, 3-stage ----------------
__global__ __launch_bounds__(256) void gate_softmax(float* __restrict__ gate, int npg) {
  int g = blockIdx.x, tid = threadIdx.x;
  __shared__ float red[256];
  size_t base = (size_t)g * npg;
  float m = -1e30f;
  for (int i = tid; i < npg; i += 256) m = fmaxf(m, gate[base + i]);
  red[tid] = m;
  __syncthreads();
  for (int s = 128; s >= 1; s >>= 1) {
    if (tid < s) red[tid] = fmaxf(red[tid], red[tid + s]);
    __syncthreads();
  }
  m = red[0];
  __syncthreads();
  float ss = 0.f;
  for (int i = tid; i < npg; i += 256) ss += __expf(gate[base + i] - m);
  red[tid] = ss;
  __syncthreads();
  for (int s = 128; s >= 1; s >>= 1) {
    if (tid < s) red[tid] += red[tid + s];
    __syncthreads();
  }
  float inv = 1.f / red[0];
  __syncthreads();
  for (int i = tid; i < npg; i += 256) gate[base + i] = __expf(gate[base + i] - m) * inv;
}

__global__ __launch_bounds__(256) void attpool_sum(const unsigned short* __restrict__ xhi,
                                                   const unsigned short* __restrict__ xlo,
                                                   const float* __restrict__ wts,
                                                   float* __restrict__ partials,
                                                   int npg, int nch) {
  int g = blockIdx.x / nch, sub = blockIdx.x % nch;
  int c = threadIdx.x;
  size_t r0 = (size_t)g * npg + sub * 32;
  float a = 0.f;
#pragma unroll 8
  for (int i = 0; i < 32; i++) {
    float v = bf2f(xhi[(r0 + i) * 256 + c]) + bf2f(xlo[(r0 + i) * 256 + c]);
    a += wts[r0 + i] * v;
  }
  partials[(size_t)blockIdx.x * 256 + c] = a;
}

__global__ __launch_bounds__(256) void attpool_reduce(const float* __restrict__ partials,
                                                      float* __restrict__ out,
                                                      int nch, int acc_flag) {
  int g = blockIdx.x, c = threadIdx.x;
  float a = 0.f;
  for (int s = 0; s < nch; s++) a += partials[((size_t)g * nch + s) * 256 + c];
  if (acc_flag) out[g * 256 + c] += a;
  else out[g * 256 + c] = a;
}

}  // namespace

extern "C" void kernel_launch(void* const* d_in, const int* in_sizes, int n_in,
                              void* d_out, int out_size, void* d_ws, size_t ws_size,
                              hipStream_t stream) {
  (void)in_sizes; (void)n_in; (void)out_size; (void)ws_size;
  const float* x       = (const float*)d_in[0];
  const int*   ei      = (const int*)d_in[1];
  const float* lin0_w  = (const float*)d_in[2];
  const float* lin0_b  = (const float*)d_in[3];
  const float* gat0_W  = (const float*)d_in[4];
  const float* gat0_as = (const float*)d_in[5];
  const float* gat0_ad = (const float*)d_in[6];
  const float* gat0_b  = (const float*)d_in[7];
  const float* pool0_w = (const float*)d_in[8];
  const float* gat1_W  = (const float*)d_in[9];
  const float* gat1_as = (const float*)d_in[10];
  const float* gat1_ad = (const float*)d_in[11];
  const float* gat1_b  = (const float*)d_in[12];
  const float* pool1_w = (const float*)d_in[13];
  const float* gate_w  = (const float*)d_in[14];
  const float* gate_b  = (const float*)d_in[15];
  float* out = (float*)d_out;
  const int* srcp = ei;
  const int* dstp = ei + NE;

  char* wsb = (char*)d_ws;
  size_t cur = 0;
  auto alloc = [&](size_t bytes) {
    void* p = wsb + cur;
    cur = (cur + bytes + 255) & ~(size_t)255;
    return p;
  };
  char* regA = (char*)alloc((size_t)NN0 * 256 * 4);        // hhi/hlo -> out0 -> {hW1,out1}
  char* regB = (char*)alloc((size_t)NN0 * 256 * 4);        // hW0 -> xs1hi/lo
  char* regD = (char*)alloc((size_t)NN0 * KP * 2 * 2);     // xhi/xlo -> xs0hi/lo
  float* a_s     = (float*)alloc((size_t)NN0 * 4 * 4);
  float* a_d     = (float*)alloc((size_t)NN0 * 4 * 4);
  int*   cursor  = (int*)alloc((size_t)NN0 * 4);
  int*   csr     = (int*)alloc((size_t)NN0 * 64 * 4);
  float* score   = (float*)alloc((size_t)NN0 * 4);
  int*   newid   = (int*)alloc((size_t)NN0 * 4);
  int*   perm    = (int*)alloc((size_t)NB * 1024 * 4);
  float* gateb   = (float*)alloc((size_t)32768 * 4);
  float* partials= (float*)alloc((size_t)NB * 32 * 256 * 4);
  float* norms   = (float*)alloc(2 * 4);
  unsigned short* whi0 = (unsigned short*)alloc((size_t)5 * 8192 * 2);
  unsigned short* wlo0 = (unsigned short*)alloc((size_t)5 * 8192 * 2);
  unsigned short* whi1 = (unsigned short*)alloc((size_t)8 * 8192 * 2);
  unsigned short* wlo1 = (unsigned short*)alloc((size_t)8 * 8192 * 2);
  unsigned short* whi2 = (unsigned short*)alloc((size_t)8 * 8192 * 2);
  unsigned short* wlo2 = (unsigned short*)alloc((size_t)8 * 8192 * 2);

  unsigned short* xhi = (unsigned short*)regD;
  unsigned short* xlo = xhi + (size_t)NN0 * KP;
  unsigned short* hhi = (unsigned short*)regA;
  unsigned short* hlo = hhi + (size_t)NN0 * 256;
  float* hW0  = (float*)regB;
  float* out0 = (float*)regA;
  unsigned short* xs0hi = (unsigned short*)regD;
  unsigned short* xs0lo = xs0hi + (size_t)32768 * 256;
  float* hW1  = (float*)regA;
  float* out1 = (float*)(regA + (size_t)32768 * 256 * 4);
  unsigned short* xs1hi = (unsigned short*)regB;
  unsigned short* xs1lo = xs1hi + (size_t)16384 * 256;

  pack_w<<<(5 * 8192 + 255) / 256, 256, 0, stream>>>(lin0_w, FIN, 5, whi0, wlo0);
  pack_w<<<(8 * 8192 + 255) / 256, 256, 0, stream>>>(gat0_W, 256, 8, whi1, wlo1);
  pack_w<<<(8 * 8192 + 255) / 256, 256, 0, stream>>>(gat1_W, 256, 8, whi2, wlo2);
  pack_x<<<(NN0 * KP + 255) / 256, 256, 0, stream>>>(x, xhi, xlo);
  pool_norms<<<1, 64, 0, stream>>>(pool0_w, pool1_w, norms);

  // ---- lin0 + ReLU -> hhi/hlo ----
  gemm_mfma<5, true, false><<<NN0 / 64, 256, 0, stream>>>(
      xhi, xlo, KP, whi0, wlo0, lin0_b, nullptr, hhi, hlo,
      nullptr, nullptr, nullptr, nullptr);

  // ---- GAT0: CSR + GEMM + node aggregation ----
  hipMemsetAsync(cursor, 0, (size_t)NN0 * 4, stream);
  scatter0<<<NE / 256, 256, 0, stream>>>(srcp, dstp, cursor, csr);
  gemm_mfma<8, false, true><<<NN0 / 64, 256, 0, stream>>>(
      hhi, hlo, 256, whi1, wlo1, nullptr, hW0, nullptr, nullptr,
      gat0_as, gat0_ad, a_s, a_d);
  gat_node16<<<NN0 / 32, 256, 0, stream>>>(cursor, csr, a_s, a_d, hW0,
                                           gat0_b, pool0_w, norms, out0, score, 6);

  // ---- pool0: top-1024 of 2048 per graph ----
  hipMemsetAsync(newid, 0xFF, (size_t)NN0 * 4, stream);
  topk_sort<<<NB, 1024, 0, stream>>>(score, 2048, 1024, perm, newid);
  gather_pool<<<32768 / 4, 256, 0, stream>>>(out0, perm, score, gate_w, gate_b,
                                             xs0hi, xs0lo, gateb, 32768, 8);
  gate_softmax<<<NB, 256, 0, stream>>>(gateb, 1024);
  attpool_sum<<<NB * 32, 256, 0, stream>>>(xs0hi, xs0lo, gateb, partials, 1024, 32);
  attpool_reduce<<<NB, 256, 0, stream>>>(partials, out, 32, 0);

  // ---- GAT1: fused remap+scatter, GEMM, aggregation ----
  hipMemsetAsync(cursor, 0, (size_t)32768 * 4, stream);
  scatter1<<<NE / 256, 256, 0, stream>>>(srcp, dstp, newid, cursor, csr);
  gemm_mfma<8, false, true><<<32768 / 64, 256, 0, stream>>>(
      xs0hi, xs0lo, 256, whi2, wlo2, nullptr, hW1, nullptr, nullptr,
      gat1_as, gat1_ad, a_s, a_d);
  gat_node16<<<32768 / 32, 256, 0, stream>>>(cursor, csr, a_s, a_d, hW1,
                                             gat1_b, pool1_w, norms + 1, out1, score, 5);

  // ---- pool1: top-512 of 1024 per graph ----
  topk_sort<<<NB, 1024, 0, stream>>>(score, 1024, 512, perm, nullptr);
  gather_pool<<<16384 / 4, 256, 0, stream>>>(out1, perm, score, gate_w, gate_b,
                                             xs1hi, xs1lo, gateb, 16384, 7);
  gate_softmax<<<NB, 256, 0, stream>>>(gateb, 512);
  attpool_sum<<<NB * 16, 256, 0, stream>>>(xs1hi, xs1lo, gateb, partials, 512, 16);
  attpool_reduce<<<NB, 256, 0, stream>>>(partials, out, 16, 1);
}

// Round 10
// 331.640 us; speedup vs baseline: 1.0870x; 1.0793x over previous
//
#include <hip/hip_runtime.h>
#include <cmath>

namespace {

constexpr int NN0 = 65536;   // nodes stage 0
constexpr int NB  = 32;      // graphs
constexpr int NE  = 524288;  // edges
constexpr int FIN = 129;
constexpr int KP  = 160;     // padded K for lin0 (5 k-tiles of 32)

typedef short bf16x8 __attribute__((ext_vector_type(8)));
typedef float f32x4 __attribute__((ext_vector_type(4)));

__device__ inline float leakyrelu(float z) { return z > 0.f ? z : 0.2f * z; }
__device__ inline float eluf(float z) { return z > 0.f ? z : expm1f(z); }

__device__ inline unsigned short f2bf(float x) {
  union { float f; unsigned int u; } v; v.f = x;
  unsigned int r = v.u + 0x7fffu + ((v.u >> 16) & 1u);
  return (unsigned short)(r >> 16);
}
__device__ inline float bf2f(unsigned short h) {
  union { unsigned int u; float f; } v; v.u = ((unsigned int)h) << 16;
  return v.f;
}

__device__ inline float4 f4fma(float4 a, float c, float4 acc) {
  acc.x += a.x * c; acc.y += a.y * c; acc.z += a.z * c; acc.w += a.w * c;
  return acc;
}
__device__ inline float4 xgrp_sum(float4 v) {
#pragma unroll
  for (int off = 16; off <= 32; off <<= 1) {
    v.x += __shfl_xor(v.x, off);
    v.y += __shfl_xor(v.y, off);
    v.z += __shfl_xor(v.z, off);
    v.w += __shfl_xor(v.w, off);
  }
  return v;
}

// XCD-aware block swizzle (bijective; NB%8==0)
__device__ inline int swz_block(int bid, int bpgl) {
  int x = bid & 7;
  int local = bid >> 3;
  int g = x + ((local >> bpgl) << 3);
  return (g << bpgl) + (local & ((1 << bpgl) - 1));
}

__device__ __forceinline__ void gload_lds16(const unsigned short* g, unsigned short* l) {
  __builtin_amdgcn_global_load_lds((const unsigned int*)g, (unsigned int*)l, 16, 0, 0);
}

// ---------------- merged prep: pack_x + 3x pack_w + norms + inits ----------
__device__ inline void pack_w_body(const float* __restrict__ W, int Kreal, int idx,
                                   unsigned short* __restrict__ hi,
                                   unsigned short* __restrict__ lo) {
  int j = idx & 7;
  int lane = (idx >> 3) & 63;
  int ct = (idx >> 9) & 15;
  int kt = idx >> 13;
  int k = kt * 32 + ((lane >> 4) << 3) + j;
  int c = ct * 16 + (lane & 15);
  float v = (k < Kreal) ? W[(size_t)k * 256 + c] : 0.f;
  unsigned short h = f2bf(v);
  hi[idx] = h;
  lo[idx] = f2bf(v - bf2f(h));
}

__global__ void prep(const float* __restrict__ x,
                     const float* __restrict__ w0, const float* __restrict__ w1,
                     const float* __restrict__ w2,
                     const float* __restrict__ pw0, const float* __restrict__ pw1,
                     unsigned short* __restrict__ xhi, unsigned short* __restrict__ xlo,
                     unsigned short* __restrict__ whi0, unsigned short* __restrict__ wlo0,
                     unsigned short* __restrict__ whi1, unsigned short* __restrict__ wlo1,
                     unsigned short* __restrict__ whi2, unsigned short* __restrict__ wlo2,
                     float* __restrict__ norms, int* __restrict__ cursor,
                     int* __restrict__ newid) {
  const int NX = NN0 * KP / 256;   // 40960 blocks: pack x
  const int NW0 = 5 * 8192 / 256;  // 160
  const int NW = 8 * 8192 / 256;   // 256
  const int NC = NN0 / 256;        // 256: cursor/newid init
  int b = blockIdx.x, tid = threadIdx.x;
  if (b < NX) {
    int idx = b * 256 + tid;
    int row = idx / KP, c = idx - row * KP;
    float v = (c < FIN) ? x[(size_t)row * FIN + c] : 0.f;
    unsigned short h = f2bf(v);
    xhi[idx] = h;
    xlo[idx] = f2bf(v - bf2f(h));
    return;
  }
  b -= NX;
  if (b < NW0) { pack_w_body(w0, FIN, b * 256 + tid, whi0, wlo0); return; }
  b -= NW0;
  if (b < NW) { pack_w_body(w1, 256, b * 256 + tid, whi1, wlo1); return; }
  b -= NW;
  if (b < NW) { pack_w_body(w2, 256, b * 256 + tid, whi2, wlo2); return; }
  b -= NW;
  if (b < NC) {
    int i = b * 256 + tid;
    cursor[i] = 0;
    newid[i] = -1;
    return;
  }
  // last block: pool-weight inverse norms (wave 0 only)
  if (tid < 64) {
    float a0 = 0.f, a1 = 0.f;
#pragma unroll
    for (int j = tid; j < 256; j += 64) {
      float v0 = pw0[j]; a0 += v0 * v0;
      float v1 = pw1[j]; a1 += v1 * v1;
    }
#pragma unroll
    for (int off = 32; off >= 1; off >>= 1) {
      a0 += __shfl_xor(a0, off);
      a1 += __shfl_xor(a1, off);
    }
    if (tid == 0) {
      norms[0] = 1.f / (sqrtf(a0) + 1e-16f);
      norms[1] = 1.f / (sqrtf(a1) + 1e-16f);
    }
  }
}

// ---------------- split-bf16 3-pass MFMA GEMM, BM=128 x BN=256 --------------
// X pre-split hi/lo bf16; staging via global_load_lds. 4 waves; wave w owns
// cols w*64..w*64+63 (== head w for ATT epilogue), all 128 rows.
template <int KT, bool RELUBIAS, bool ATT>
__global__ __launch_bounds__(256, 2) void gemm_mfma(
    const unsigned short* __restrict__ Xhi, const unsigned short* __restrict__ Xlo,
    int ldx,
    const unsigned short* __restrict__ Bhi, const unsigned short* __restrict__ Blo,
    const float* __restrict__ bias,
    float* __restrict__ Out,
    unsigned short* __restrict__ OutHi, unsigned short* __restrict__ OutLo,
    const float* __restrict__ attsrc, const float* __restrict__ attdst,
    float* __restrict__ a_s, float* __restrict__ a_d) {
  __shared__ __align__(16) unsigned short As[2][2][128][32];  // 32 KB
  const int tid = threadIdx.x;
  const int lane = tid & 63;
  const int w = tid >> 6;
  const int row0 = blockIdx.x * 128;
  const int l15 = lane & 15, q = lane >> 4;
  const int sl4 = lane >> 2;          // 0..15: staging row within 16-row strip
  const int skc = (lane & 3) * 8;     // staging k-offset (8 bf16 = 16B)

  auto stage = [&](int nb, int kt) {
#pragma unroll
    for (int i = 0; i < 2; i++) {
      const int rbase = (w + 4 * i) * 16;
      const size_t goff = (size_t)(row0 + rbase + sl4) * ldx + kt * 32 + skc;
      gload_lds16(Xhi + goff, &As[nb][0][rbase][0]);
      gload_lds16(Xlo + goff, &As[nb][1][rbase][0]);
    }
  };

  f32x4 acc[8][4];
#pragma unroll
  for (int mf = 0; mf < 8; mf++)
#pragma unroll
    for (int nf = 0; nf < 4; nf++) acc[mf][nf] = (f32x4)(0.f);

  stage(0, 0);
  __syncthreads();

#pragma unroll
  for (int kt = 0; kt < KT; ++kt) {
    const int nb = kt & 1;
    if (kt + 1 < KT) stage(nb ^ 1, kt + 1);
    bf16x8 bh[4], bl[4];
#pragma unroll
    for (int nf = 0; nf < 4; nf++) {
      const int ct = w * 4 + nf;
      const size_t bbase = ((size_t)((kt * 16 + ct) * 64 + lane)) << 3;
      bh[nf] = *reinterpret_cast<const bf16x8*>(Bhi + bbase);
      bl[nf] = *reinterpret_cast<const bf16x8*>(Blo + bbase);
    }
#pragma unroll
    for (int mf = 0; mf < 8; mf++) {
      const int ar = mf * 16 + l15;
      bf16x8 ah = *reinterpret_cast<const bf16x8*>(&As[nb][0][ar][q * 8]);
      bf16x8 al = *reinterpret_cast<const bf16x8*>(&As[nb][1][ar][q * 8]);
#pragma unroll
      for (int nf = 0; nf < 4; nf++) {
        acc[mf][nf] = __builtin_amdgcn_mfma_f32_16x16x32_bf16(ah, bh[nf], acc[mf][nf], 0, 0, 0);
        acc[mf][nf] = __builtin_amdgcn_mfma_f32_16x16x32_bf16(ah, bl[nf], acc[mf][nf], 0, 0, 0);
        acc[mf][nf] = __builtin_amdgcn_mfma_f32_16x16x32_bf16(al, bh[nf], acc[mf][nf], 0, 0, 0);
      }
    }
    __syncthreads();
  }

#pragma unroll
  for (int mf = 0; mf < 8; mf++) {
    const int rowb = row0 + mf * 16 + q * 4;
#pragma unroll
    for (int r = 0; r < 4; r++) {
#pragma unroll
      for (int nf = 0; nf < 4; nf++) {
        float v = acc[mf][nf][r];
        const int col = w * 64 + nf * 16 + l15;
        if constexpr (RELUBIAS) {
          v += bias[col];
          v = fmaxf(v, 0.f);
          unsigned short h = f2bf(v);
          OutHi[(size_t)(rowb + r) * 256 + col] = h;
          OutLo[(size_t)(rowb + r) * 256 + col] = f2bf(v - bf2f(h));
        } else {
          Out[(size_t)(rowb + r) * 256 + col] = v;
        }
      }
    }
  }
  if constexpr (ATT) {
    const int head = w;
    float sv[4], dv[4];
#pragma unroll
    for (int nf = 0; nf < 4; nf++) {
      sv[nf] = attsrc[head * 64 + nf * 16 + l15];
      dv[nf] = attdst[head * 64 + nf * 16 + l15];
    }
#pragma unroll
    for (int mf = 0; mf < 8; mf++) {
#pragma unroll
      for (int r = 0; r < 4; r++) {
        float ps = 0.f, pd = 0.f;
#pragma unroll
        for (int nf = 0; nf < 4; nf++) {
          ps += acc[mf][nf][r] * sv[nf];
          pd += acc[mf][nf][r] * dv[nf];
        }
#pragma unroll
        for (int off = 8; off >= 1; off >>= 1) {
          ps += __shfl_xor(ps, off);
          pd += __shfl_xor(pd, off);
        }
        if (l15 == 0) {
          const int row = row0 + mf * 16 + q * 4 + r;
          a_s[(size_t)row * 4 + head] = ps;
          a_d[(size_t)row * 4 + head] = pd;
        }
      }
    }
  }
}

// ---------------- stride-64 CSR scatter ----------------
__global__ void scatter0(const int* __restrict__ src, const int* __restrict__ dst,
                         int* __restrict__ cursor, int* __restrict__ csr) {
  int e = blockIdx.x * blockDim.x + threadIdx.x;
  if (e >= NE) return;
  int d = dst[e];
  int pos = atomicAdd(&cursor[d], 1);
  if (pos < 64) csr[(size_t)d * 64 + pos] = src[e];
}

__global__ void scatter1(const int* __restrict__ src, const int* __restrict__ dst,
                         const int* __restrict__ newid,
                         int* __restrict__ cursor, int* __restrict__ csr) {
  int e = blockIdx.x * blockDim.x + threadIdx.x;
  if (e >= NE) return;
  int s = newid[src[e]], d = newid[dst[e]];
  if (s < 0 || d < 0) return;
  int pos = atomicAdd(&cursor[d], 1);
  if (pos < 64) csr[(size_t)d * 64 + pos] = s;
}

// --------- per-dest-node GAT: 4 nodes/wave, 16 lanes each (R6 structure) ----
__global__ __launch_bounds__(256) void gat_node16(
    const int* __restrict__ cursor, const int* __restrict__ csr,
    const float* __restrict__ a_s, const float* __restrict__ a_d,
    const float* __restrict__ hW, const float* __restrict__ bias,
    const float* __restrict__ pool_w, const float* __restrict__ inv_norm,
    float* __restrict__ out, float* __restrict__ score, int bpgl) {
  const int lane = threadIdx.x & 63;
  const int wv = threadIdx.x >> 6;
  const int dbase = swz_block(blockIdx.x, bpgl) * 16 + wv * 4;
  const int p = lane >> 4, l16 = lane & 15;

  const int d = dbase + p;
  const int deg = min(cursor[d], 63);
  const int dim = deg + 1;  // + self loop

  if (__all(dim <= 16)) {
    const float4 ad4 = *reinterpret_cast<const float4*>(&a_d[(size_t)d * 4]);
    const bool has = l16 < dim;
    int s = (l16 < deg) ? csr[(size_t)d * 64 + l16] : d;
    float4 as4 = *reinterpret_cast<const float4*>(&a_s[(size_t)s * 4]);
    float l0 = leakyrelu(as4.x + ad4.x);
    float l1 = leakyrelu(as4.y + ad4.y);
    float l2 = leakyrelu(as4.z + ad4.z);
    float l3 = leakyrelu(as4.w + ad4.w);
    float m0 = has ? l0 : -1e30f, m1 = has ? l1 : -1e30f;
    float m2 = has ? l2 : -1e30f, m3 = has ? l3 : -1e30f;
#pragma unroll
    for (int off = 1; off <= 8; off <<= 1) {   // 16-lane group reduce
      m0 = fmaxf(m0, __shfl_xor(m0, off));
      m1 = fmaxf(m1, __shfl_xor(m1, off));
      m2 = fmaxf(m2, __shfl_xor(m2, off));
      m3 = fmaxf(m3, __shfl_xor(m3, off));
    }
    float e0 = has ? __expf(l0 - m0) : 0.f;
    float e1 = has ? __expf(l1 - m1) : 0.f;
    float e2 = has ? __expf(l2 - m2) : 0.f;
    float e3 = has ? __expf(l3 - m3) : 0.f;
    float dn0 = e0, dn1 = e1, dn2 = e2, dn3 = e3;
#pragma unroll
    for (int off = 1; off <= 8; off <<= 1) {
      dn0 += __shfl_xor(dn0, off);
      dn1 += __shfl_xor(dn1, off);
      dn2 += __shfl_xor(dn2, off);
      dn3 += __shfl_xor(dn3, off);
    }
    int dmax = dim;
    dmax = max(dmax, __shfl_xor(dmax, 16));
    dmax = max(dmax, __shfl_xor(dmax, 32));
    float4 acc[4];
#pragma unroll
    for (int h = 0; h < 4; h++) acc[h] = float4{0.f, 0.f, 0.f, 0.f};
#pragma unroll 2
    for (int t = 0; t < dmax; t++) {
      const int idx = p * 16 + t;
      int st = __shfl(s, idx);
      float c0 = __shfl(e0, idx), c1 = __shfl(e1, idx);
      float c2 = __shfl(e2, idx), c3 = __shfl(e3, idx);
      if (t < dim) {
        const float4* hp = reinterpret_cast<const float4*>(&hW[(size_t)st * 256]) + l16;
        acc[0] = f4fma(hp[0],  c0, acc[0]);
        acc[1] = f4fma(hp[16], c1, acc[1]);
        acc[2] = f4fma(hp[32], c2, acc[2]);
        acc[3] = f4fma(hp[48], c3, acc[3]);
      }
    }
    const float inv[4] = {1.f / (dn0 + 1e-16f), 1.f / (dn1 + 1e-16f),
                          1.f / (dn2 + 1e-16f), 1.f / (dn3 + 1e-16f)};
    float sd = 0.f;
#pragma unroll
    for (int h = 0; h < 4; h++) {
      const int coff = h * 64 + l16 * 4;
      float4 bb = *reinterpret_cast<const float4*>(&bias[coff]);
      float4 o;
      o.x = eluf(acc[h].x * inv[h] + bb.x);
      o.y = eluf(acc[h].y * inv[h] + bb.y);
      o.z = eluf(acc[h].z * inv[h] + bb.z);
      o.w = eluf(acc[h].w * inv[h] + bb.w);
      *reinterpret_cast<float4*>(&out[(size_t)d * 256 + coff]) = o;
      float4 pw = *reinterpret_cast<const float4*>(&pool_w[coff]);
      sd += o.x * pw.x + o.y * pw.y + o.z * pw.z + o.w * pw.w;
    }
#pragma unroll
    for (int off = 1; off <= 8; off <<= 1) sd += __shfl_xor(sd, off);
    if (l16 == 0) score[d] = sd * inv_norm[0];
    return;
  }

  // ---- fallback: full wave per node, 4 nodes sequentially (dim <= 64) ----
  for (int pp = 0; pp < 4; pp++) {
    const int dd = dbase + pp;
    const int degp = min(cursor[dd], 63);
    const int dimp = degp + 1;
    const float4 add4 = *reinterpret_cast<const float4*>(&a_d[(size_t)dd * 4]);
    const bool has = lane < dimp;
    int s = (lane < degp) ? csr[(size_t)dd * 64 + lane] : dd;
    float4 as4 = *reinterpret_cast<const float4*>(&a_s[(size_t)s * 4]);
    float l0 = leakyrelu(as4.x + add4.x);
    float l1 = leakyrelu(as4.y + add4.y);
    float l2 = leakyrelu(as4.z + add4.z);
    float l3 = leakyrelu(as4.w + add4.w);
    float m0 = has ? l0 : -1e30f, m1 = has ? l1 : -1e30f;
    float m2 = has ? l2 : -1e30f, m3 = has ? l3 : -1e30f;
#pragma unroll
    for (int off = 1; off <= 32; off <<= 1) {
      m0 = fmaxf(m0, __shfl_xor(m0, off));
      m1 = fmaxf(m1, __shfl_xor(m1, off));
      m2 = fmaxf(m2, __shfl_xor(m2, off));
      m3 = fmaxf(m3, __shfl_xor(m3, off));
    }
    float e0 = has ? __expf(l0 - m0) : 0.f;
    float e1 = has ? __expf(l1 - m1) : 0.f;
    float e2 = has ? __expf(l2 - m2) : 0.f;
    float e3 = has ? __expf(l3 - m3) : 0.f;
    float dn0 = e0, dn1 = e1, dn2 = e2, dn3 = e3;
#pragma unroll
    for (int off = 1; off <= 32; off <<= 1) {
      dn0 += __shfl_xor(dn0, off);
      dn1 += __shfl_xor(dn1, off);
      dn2 += __shfl_xor(dn2, off);
      dn3 += __shfl_xor(dn3, off);
    }
    float4 acc0 = {0,0,0,0}, acc1 = {0,0,0,0}, acc2 = {0,0,0,0}, acc3 = {0,0,0,0};
    for (int base = 0; base < dimp; base += 4) {
      int t = base + p;
      int tc = (t < dimp) ? t : 0;
      int st = __shfl(s, tc);
      float c0 = __shfl(e0, tc), c1 = __shfl(e1, tc);
      float c2 = __shfl(e2, tc), c3 = __shfl(e3, tc);
      if (t < dimp) {
        const float4* hp = reinterpret_cast<const float4*>(&hW[(size_t)st * 256]) + l16;
        acc0 = f4fma(hp[0],  c0, acc0);
        acc1 = f4fma(hp[16], c1, acc1);
        acc2 = f4fma(hp[32], c2, acc2);
        acc3 = f4fma(hp[48], c3, acc3);
      }
    }
    acc0 = xgrp_sum(acc0); acc1 = xgrp_sum(acc1);
    acc2 = xgrp_sum(acc2); acc3 = xgrp_sum(acc3);
    const float inv0 = 1.f / (dn0 + 1e-16f), inv1 = 1.f / (dn1 + 1e-16f);
    const float inv2 = 1.f / (dn2 + 1e-16f), inv3 = 1.f / (dn3 + 1e-16f);
    float4 vb = (p == 0) ? acc0 : (p == 1) ? acc1 : (p == 2) ? acc2 : acc3;
    float invg = (p == 0) ? inv0 : (p == 1) ? inv1 : (p == 2) ? inv2 : inv3;
    const int coff = p * 64 + l16 * 4;
    float4 bb = *reinterpret_cast<const float4*>(&bias[coff]);
    float4 o;
    o.x = eluf(vb.x * invg + bb.x);
    o.y = eluf(vb.y * invg + bb.y);
    o.z = eluf(vb.z * invg + bb.z);
    o.w = eluf(vb.w * invg + bb.w);
    *reinterpret_cast<float4*>(&out[(size_t)dd * 256 + coff]) = o;
    float4 pw = *reinterpret_cast<const float4*>(&pool_w[coff]);
    float sd = o.x * pw.x + o.y * pw.y + o.z * pw.z + o.w * pw.w;
#pragma unroll
    for (int off = 1; off <= 32; off <<= 1) sd += __shfl_xor(sd, off);
    if (lane == 0) score[dd] = sd * inv_norm[0];
  }
}

// ---------------- per-graph bitonic top-k sort ----------------
__global__ __launch_bounds__(1024) void topk_sort(const float* __restrict__ score,
                                                  int npg, int k,
                                                  int* __restrict__ perm,
                                                  int* __restrict__ newid) {
  __shared__ float sv[2048];
  __shared__ int si[2048];
  int g = blockIdx.x;
  for (int i = threadIdx.x; i < npg; i += blockDim.x) {
    sv[i] = score[(size_t)g * npg + i];
    si[i] = i;
  }
  __syncthreads();
  for (int size = 2; size <= npg; size <<= 1) {
    for (int stride = size >> 1; stride > 0; stride >>= 1) {
      for (int i = threadIdx.x; i < npg; i += blockDim.x) {
        int j = i ^ stride;
        if (j > i) {
          bool desc = ((i & size) == 0);
          float vi = sv[i], vj = sv[j];
          int ii = si[i], ij = si[j];
          bool i_before_j = (vi > vj) || (vi == vj && ii < ij);
          bool doswap = desc ? !i_before_j : i_before_j;
          if (doswap) { sv[i] = vj; sv[j] = vi; si[i] = ij; si[j] = ii; }
        }
      }
      __syncthreads();
    }
  }
  for (int j = threadIdx.x; j < k; j += blockDim.x) {
    int node = g * npg + si[j];
    perm[g * k + j] = node;
    if (newid) newid[node] = g * k + j;
  }
}

// ------- pooled gather + gate dot; emits hi/lo bf16 slabs for next GEMM -----
__global__ void gather_pool(const float* __restrict__ hx, const int* __restrict__ perm,
                            const float* __restrict__ score,
                            const float* __restrict__ gate_w, const float* __restrict__ gate_b,
                            unsigned short* __restrict__ xshi, unsigned short* __restrict__ xslo,
                            float* __restrict__ gate, int nrows, int bpgl) {
  int j = swz_block(blockIdx.x, bpgl) * 4 + (threadIdx.x >> 6);
  int lane = threadIdx.x & 63;
  if (j >= nrows) return;
  int node = perm[j];
  float tsc = tanhf(score[node]);
  float4 v = reinterpret_cast<const float4*>(&hx[(size_t)node * 256])[lane];
  v.x *= tsc; v.y *= tsc; v.z *= tsc; v.w *= tsc;
  ushort4 h4, l4;
  h4.x = f2bf(v.x); l4.x = f2bf(v.x - bf2f(h4.x));
  h4.y = f2bf(v.y); l4.y = f2bf(v.y - bf2f(h4.y));
  h4.z = f2bf(v.z); l4.z = f2bf(v.z - bf2f(h4.z));
  h4.w = f2bf(v.w); l4.w = f2bf(v.w - bf2f(h4.w));
  *reinterpret_cast<ushort4*>(&xshi[(size_t)j * 256 + lane * 4]) = h4;
  *reinterpret_cast<ushort4*>(&xslo[(size_t)j * 256 + lane * 4]) = l4;
  float4 gw = reinterpret_cast<const float4*>(gate_w)[lane];
  float gd = v.x * gw.x + v.y * gw.y + v.z * gw.z + v.w * gw.w;
#pragma unroll
  for (int off = 32; off >= 1; off >>= 1) gd += __shfl_xor(gd, off);
  if (lane == 0) gate[j] = gd + gate_b[0];
}

// ---------------- attention pooling, 3-stage ----------------
__global__ __launch_bounds__(256) void gate_softmax(float* __restrict__ gate, int npg) {
  int g = blockIdx.x, tid = threadIdx.x;
  __shared__ float red[256];
  size_t base = (size_t)g * npg;
  float m = -1e30f;
  for (int i = tid; i < npg; i += 256) m = fmaxf(m, gate[base + i]);
  red[tid] = m;
  __syncthreads();
  for (int s = 128; s >= 1; s >>= 1) {
    if (tid < s) red[tid] = fmaxf(red[tid], red[tid + s]);
    __syncthreads();
  }
  m = red[0];
  __syncthreads();
  float ss = 0.f;
  for (int i = tid; i < npg; i += 256) ss += __expf(gate[base + i] - m);
  red[tid] = ss;
  __syncthreads();
  for (int s = 128; s >= 1; s >>= 1) {
    if (tid < s) red[tid] += red[tid + s];
    __syncthreads();
  }
  float inv = 1.f / red[0];
  __syncthreads();
  for (int i = tid; i < npg; i += 256) gate[base + i] = __expf(gate[base + i] - m) * inv;
}

__global__ __launch_bounds__(256) void attpool_sum(const unsigned short* __restrict__ xhi,
                                                   const unsigned short* __restrict__ xlo,
                                                   const float* __restrict__ wts,
                                                   float* __restrict__ partials,
                                                   int npg, int nch) {
  int g = blockIdx.x / nch, sub = blockIdx.x % nch;
  int c = threadIdx.x;
  size_t r0 = (size_t)g * npg + sub * 32;
  float a = 0.f;
#pragma unroll 8
  for (int i = 0; i < 32; i++) {
    float v = bf2f(xhi[(r0 + i) * 256 + c]) + bf2f(xlo[(r0 + i) * 256 + c]);
    a += wts[r0 + i] * v;
  }
  partials[(size_t)blockIdx.x * 256 + c] = a;
}

__global__ __launch_bounds__(256) void attpool_reduce(const float* __restrict__ partials,
                                                      float* __restrict__ out,
                                                      int nch, int acc_flag) {
  int g = blockIdx.x, c = threadIdx.x;
  float a = 0.f;
  for (int s = 0; s < nch; s++) a += partials[((size_t)g * nch + s) * 256 + c];
  if (acc_flag) out[g * 256 + c] += a;
  else out[g * 256 + c] = a;
}

}  // namespace

extern "C" void kernel_launch(void* const* d_in, const int* in_sizes, int n_in,
                              void* d_out, int out_size, void* d_ws, size_t ws_size,
                              hipStream_t stream) {
  (void)in_sizes; (void)n_in; (void)out_size; (void)ws_size;
  const float* x       = (const float*)d_in[0];
  const int*   ei      = (const int*)d_in[1];
  const float* lin0_w  = (const float*)d_in[2];
  const float* lin0_b  = (const float*)d_in[3];
  const float* gat0_W  = (const float*)d_in[4];
  const float* gat0_as = (const float*)d_in[5];
  const float* gat0_ad = (const float*)d_in[6];
  const float* gat0_b  = (const float*)d_in[7];
  const float* pool0_w = (const float*)d_in[8];
  const float* gat1_W  = (const float*)d_in[9];
  const float* gat1_as = (const float*)d_in[10];
  const float* gat1_ad = (const float*)d_in[11];
  const float* gat1_b  = (const float*)d_in[12];
  const float* pool1_w = (const float*)d_in[13];
  const float* gate_w  = (const float*)d_in[14];
  const float* gate_b  = (const float*)d_in[15];
  float* out = (float*)d_out;
  const int* srcp = ei;
  const int* dstp = ei + NE;

  char* wsb = (char*)d_ws;
  size_t cur = 0;
  auto alloc = [&](size_t bytes) {
    void* p = wsb + cur;
    cur = (cur + bytes + 255) & ~(size_t)255;
    return p;
  };
  char* regA = (char*)alloc((size_t)NN0 * 256 * 4);        // hhi/hlo -> out0 -> {hW1,out1}
  char* regB = (char*)alloc((size_t)NN0 * 256 * 4);        // hW0 -> xs1hi/lo
  char* regD = (char*)alloc((size_t)NN0 * KP * 2 * 2);     // xhi/xlo -> xs0hi/lo
  float* a_s     = (float*)alloc((size_t)NN0 * 4 * 4);
  float* a_d     = (float*)alloc((size_t)NN0 * 4 * 4);
  int*   cursor  = (int*)alloc((size_t)NN0 * 4);
  int*   csr     = (int*)alloc((size_t)NN0 * 64 * 4);
  float* score   = (float*)alloc((size_t)NN0 * 4);
  int*   newid   = (int*)alloc((size_t)NN0 * 4);
  int*   perm    = (int*)alloc((size_t)NB * 1024 * 4);
  float* gateb   = (float*)alloc((size_t)32768 * 4);
  float* partials= (float*)alloc((size_t)NB * 32 * 256 * 4);
  float* norms   = (float*)alloc(2 * 4);
  unsigned short* whi0 = (unsigned short*)alloc((size_t)5 * 8192 * 2);
  unsigned short* wlo0 = (unsigned short*)alloc((size_t)5 * 8192 * 2);
  unsigned short* whi1 = (unsigned short*)alloc((size_t)8 * 8192 * 2);
  unsigned short* wlo1 = (unsigned short*)alloc((size_t)8 * 8192 * 2);
  unsigned short* whi2 = (unsigned short*)alloc((size_t)8 * 8192 * 2);
  unsigned short* wlo2 = (unsigned short*)alloc((size_t)8 * 8192 * 2);

  unsigned short* xhi = (unsigned short*)regD;
  unsigned short* xlo = xhi + (size_t)NN0 * KP;
  unsigned short* hhi = (unsigned short*)regA;
  unsigned short* hlo = hhi + (size_t)NN0 * 256;
  float* hW0  = (float*)regB;
  float* out0 = (float*)regA;
  unsigned short* xs0hi = (unsigned short*)regD;
  unsigned short* xs0lo = xs0hi + (size_t)32768 * 256;
  float* hW1  = (float*)regA;
  float* out1 = (float*)(regA + (size_t)32768 * 256 * 4);
  unsigned short* xs1hi = (unsigned short*)regB;
  unsigned short* xs1lo = xs1hi + (size_t)16384 * 256;

  // ---- merged prep: pack x, pack 3x W, pool norms, cursor=0, newid=-1 ----
  {
    int grid = NN0 * KP / 256 + 160 + 256 + 256 + 256 + 1;
    prep<<<grid, 256, 0, stream>>>(x, lin0_w, gat0_W, gat1_W, pool0_w, pool1_w,
                                   xhi, xlo, whi0, wlo0, whi1, wlo1, whi2, wlo2,
                                   norms, cursor, newid);
  }

  // ---- lin0 + ReLU -> hhi/hlo ----
  gemm_mfma<5, true, false><<<NN0 / 128, 256, 0, stream>>>(
      xhi, xlo, KP, whi0, wlo0, lin0_b, nullptr, hhi, hlo,
      nullptr, nullptr, nullptr, nullptr);

  // ---- GAT0: CSR + GEMM + node aggregation ----
  scatter0<<<NE / 256, 256, 0, stream>>>(srcp, dstp, cursor, csr);
  gemm_mfma<8, false, true><<<NN0 / 128, 256, 0, stream>>>(
      hhi, hlo, 256, whi1, wlo1, nullptr, hW0, nullptr, nullptr,
      gat0_as, gat0_ad, a_s, a_d);
  gat_node16<<<NN0 / 16, 256, 0, stream>>>(cursor, csr, a_s, a_d, hW0,
                                           gat0_b, pool0_w, norms, out0, score, 7);

  // ---- pool0: top-1024 of 2048 per graph ----
  topk_sort<<<NB, 1024, 0, stream>>>(score, 2048, 1024, perm, newid);
  gather_pool<<<32768 / 4, 256, 0, stream>>>(out0, perm, score, gate_w, gate_b,
                                             xs0hi, xs0lo, gateb, 32768, 8);
  gate_softmax<<<NB, 256, 0, stream>>>(gateb, 1024);
  attpool_sum<<<NB * 32, 256, 0, stream>>>(xs0hi, xs0lo, gateb, partials, 1024, 32);
  attpool_reduce<<<NB, 256, 0, stream>>>(partials, out, 32, 0);

  // ---- GAT1: fused remap+scatter, GEMM, aggregation ----
  hipMemsetAsync(cursor, 0, (size_t)32768 * 4, stream);
  scatter1<<<NE / 256, 256, 0, stream>>>(srcp, dstp, newid, cursor, csr);
  gemm_mfma<8, false, true><<<32768 / 128, 256, 0, stream>>>(
      xs0hi, xs0lo, 256, whi2, wlo2, nullptr, hW1, nullptr, nullptr,
      gat1_as, gat1_ad, a_s, a_d);
  gat_node16<<<32768 / 16, 256, 0, stream>>>(cursor, csr, a_s, a_d, hW1,
                                             gat1_b, pool1_w, norms + 1, out1, score, 6);

  // ---- pool1: top-512 of 1024 per graph ----
  topk_sort<<<NB, 1024, 0, stream>>>(score, 1024, 512, perm, nullptr);
  gather_pool<<<16384 / 4, 256, 0, stream>>>(out1, perm, score, gate_w, gate_b,
                                             xs1hi, xs1lo, gateb, 16384, 7);
  gate_softmax<<<NB, 256, 0, stream>>>(gateb, 512);
  attpool_sum<<<NB * 16, 256, 0, stream>>>(xs1hi, xs1lo, gateb, partials, 512, 16);
  attpool_reduce<<<NB, 256, 0, stream>>>(partials, out, 16, 1);
}

// Round 11
// 325.892 us; speedup vs baseline: 1.1062x; 1.0176x over previous
//
#include <hip/hip_runtime.h>
#include <cmath>

namespace {

constexpr int NN0 = 65536;   // nodes stage 0
constexpr int NB  = 32;      // graphs
constexpr int NE  = 524288;  // edges
constexpr int FIN = 129;
constexpr int KP  = 160;     // padded K for lin0 (5 k-tiles of 32)

typedef short bf16x8 __attribute__((ext_vector_type(8)));
typedef float f32x4 __attribute__((ext_vector_type(4)));

__device__ inline float leakyrelu(float z) { return z > 0.f ? z : 0.2f * z; }
__device__ inline float eluf(float z) { return z > 0.f ? z : expm1f(z); }

__device__ inline unsigned short f2bf(float x) {
  union { float f; unsigned int u; } v; v.f = x;
  unsigned int r = v.u + 0x7fffu + ((v.u >> 16) & 1u);
  return (unsigned short)(r >> 16);
}
__device__ inline float bf2f(unsigned short h) {
  union { unsigned int u; float f; } v; v.u = ((unsigned int)h) << 16;
  return v.f;
}

__device__ inline float4 f4fma(float4 a, float c, float4 acc) {
  acc.x += a.x * c; acc.y += a.y * c; acc.z += a.z * c; acc.w += a.w * c;
  return acc;
}

// XCD-aware block swizzle (bijective; NB%8==0)
__device__ inline int swz_block(int bid, int bpgl) {
  int x = bid & 7;
  int local = bid >> 3;
  int g = x + ((local >> bpgl) << 3);
  return (g << bpgl) + (local & ((1 << bpgl) - 1));
}

__device__ __forceinline__ void gload_lds16(const unsigned short* g, unsigned short* l) {
  __builtin_amdgcn_global_load_lds((const unsigned int*)g, (unsigned int*)l, 16, 0, 0);
}

// ---------------- merged prep: pack_x + 3x pack_w + norms + inits ----------
__device__ inline void pack_w_body(const float* __restrict__ W, int Kreal, int idx,
                                   unsigned short* __restrict__ hi,
                                   unsigned short* __restrict__ lo) {
  int j = idx & 7;
  int lane = (idx >> 3) & 63;
  int ct = (idx >> 9) & 15;
  int kt = idx >> 13;
  int k = kt * 32 + ((lane >> 4) << 3) + j;
  int c = ct * 16 + (lane & 15);
  float v = (k < Kreal) ? W[(size_t)k * 256 + c] : 0.f;
  unsigned short h = f2bf(v);
  hi[idx] = h;
  lo[idx] = f2bf(v - bf2f(h));
}

__global__ void prep(const float* __restrict__ x,
                     const float* __restrict__ w0, const float* __restrict__ w1,
                     const float* __restrict__ w2,
                     const float* __restrict__ pw0, const float* __restrict__ pw1,
                     unsigned short* __restrict__ xhi, unsigned short* __restrict__ xlo,
                     unsigned short* __restrict__ whi0, unsigned short* __restrict__ wlo0,
                     unsigned short* __restrict__ whi1, unsigned short* __restrict__ wlo1,
                     unsigned short* __restrict__ whi2, unsigned short* __restrict__ wlo2,
                     float* __restrict__ norms, int* __restrict__ cursor,
                     int* __restrict__ cursor2, int* __restrict__ newid) {
  const int NX = NN0 * KP / 256;   // 40960 blocks: pack x
  const int NW0 = 5 * 8192 / 256;  // 160
  const int NW = 8 * 8192 / 256;   // 256
  const int NC = NN0 / 256;        // 256: cursor/newid init
  int b = blockIdx.x, tid = threadIdx.x;
  if (b < NX) {
    int idx = b * 256 + tid;
    int row = idx / KP, c = idx - row * KP;
    float v = (c < FIN) ? x[(size_t)row * FIN + c] : 0.f;
    unsigned short h = f2bf(v);
    xhi[idx] = h;
    xlo[idx] = f2bf(v - bf2f(h));
    return;
  }
  b -= NX;
  if (b < NW0) { pack_w_body(w0, FIN, b * 256 + tid, whi0, wlo0); return; }
  b -= NW0;
  if (b < NW) { pack_w_body(w1, 256, b * 256 + tid, whi1, wlo1); return; }
  b -= NW;
  if (b < NW) { pack_w_body(w2, 256, b * 256 + tid, whi2, wlo2); return; }
  b -= NW;
  if (b < NC) {
    int i = b * 256 + tid;
    cursor[i] = 0;
    newid[i] = -1;
    if (i < 32768) cursor2[i] = 0;
    return;
  }
  // last block: pool-weight inverse norms (wave 0 only)
  if (tid < 64) {
    float a0 = 0.f, a1 = 0.f;
#pragma unroll
    for (int j = tid; j < 256; j += 64) {
      float v0 = pw0[j]; a0 += v0 * v0;
      float v1 = pw1[j]; a1 += v1 * v1;
    }
#pragma unroll
    for (int off = 32; off >= 1; off >>= 1) {
      a0 += __shfl_xor(a0, off);
      a1 += __shfl_xor(a1, off);
    }
    if (tid == 0) {
      norms[0] = 1.f / (sqrtf(a0) + 1e-16f);
      norms[1] = 1.f / (sqrtf(a1) + 1e-16f);
    }
  }
}

// ---------------- split-bf16 3-pass MFMA GEMM, BM=128 x BN=256 --------------
template <int KT, bool RELUBIAS, bool ATT>
__global__ __launch_bounds__(256, 2) void gemm_mfma(
    const unsigned short* __restrict__ Xhi, const unsigned short* __restrict__ Xlo,
    int ldx,
    const unsigned short* __restrict__ Bhi, const unsigned short* __restrict__ Blo,
    const float* __restrict__ bias,
    float* __restrict__ Out,
    unsigned short* __restrict__ OutHi, unsigned short* __restrict__ OutLo,
    const float* __restrict__ attsrc, const float* __restrict__ attdst,
    float* __restrict__ a_s, float* __restrict__ a_d) {
  __shared__ __align__(16) unsigned short As[2][2][128][32];  // 32 KB
  const int tid = threadIdx.x;
  const int lane = tid & 63;
  const int w = tid >> 6;
  const int row0 = blockIdx.x * 128;
  const int l15 = lane & 15, q = lane >> 4;
  const int sl4 = lane >> 2;
  const int skc = (lane & 3) * 8;

  auto stage = [&](int nb, int kt) {
#pragma unroll
    for (int i = 0; i < 2; i++) {
      const int rbase = (w + 4 * i) * 16;
      const size_t goff = (size_t)(row0 + rbase + sl4) * ldx + kt * 32 + skc;
      gload_lds16(Xhi + goff, &As[nb][0][rbase][0]);
      gload_lds16(Xlo + goff, &As[nb][1][rbase][0]);
    }
  };

  f32x4 acc[8][4];
#pragma unroll
  for (int mf = 0; mf < 8; mf++)
#pragma unroll
    for (int nf = 0; nf < 4; nf++) acc[mf][nf] = (f32x4)(0.f);

  stage(0, 0);
  __syncthreads();

#pragma unroll
  for (int kt = 0; kt < KT; ++kt) {
    const int nb = kt & 1;
    if (kt + 1 < KT) stage(nb ^ 1, kt + 1);
    bf16x8 bh[4], bl[4];
#pragma unroll
    for (int nf = 0; nf < 4; nf++) {
      const int ct = w * 4 + nf;
      const size_t bbase = ((size_t)((kt * 16 + ct) * 64 + lane)) << 3;
      bh[nf] = *reinterpret_cast<const bf16x8*>(Bhi + bbase);
      bl[nf] = *reinterpret_cast<const bf16x8*>(Blo + bbase);
    }
#pragma unroll
    for (int mf = 0; mf < 8; mf++) {
      const int ar = mf * 16 + l15;
      bf16x8 ah = *reinterpret_cast<const bf16x8*>(&As[nb][0][ar][q * 8]);
      bf16x8 al = *reinterpret_cast<const bf16x8*>(&As[nb][1][ar][q * 8]);
#pragma unroll
      for (int nf = 0; nf < 4; nf++) {
        acc[mf][nf] = __builtin_amdgcn_mfma_f32_16x16x32_bf16(ah, bh[nf], acc[mf][nf], 0, 0, 0);
        acc[mf][nf] = __builtin_amdgcn_mfma_f32_16x16x32_bf16(ah, bl[nf], acc[mf][nf], 0, 0, 0);
        acc[mf][nf] = __builtin_amdgcn_mfma_f32_16x16x32_bf16(al, bh[nf], acc[mf][nf], 0, 0, 0);
      }
    }
    __syncthreads();
  }

#pragma unroll
  for (int mf = 0; mf < 8; mf++) {
    const int rowb = row0 + mf * 16 + q * 4;
#pragma unroll
    for (int r = 0; r < 4; r++) {
#pragma unroll
      for (int nf = 0; nf < 4; nf++) {
        float v = acc[mf][nf][r];
        const int col = w * 64 + nf * 16 + l15;
        if constexpr (RELUBIAS) {
          v += bias[col];
          v = fmaxf(v, 0.f);
          unsigned short h = f2bf(v);
          OutHi[(size_t)(rowb + r) * 256 + col] = h;
          OutLo[(size_t)(rowb + r) * 256 + col] = f2bf(v - bf2f(h));
        } else {
          Out[(size_t)(rowb + r) * 256 + col] = v;
        }
      }
    }
  }
  if constexpr (ATT) {
    const int head = w;
    float sv[4], dv[4];
#pragma unroll
    for (int nf = 0; nf < 4; nf++) {
      sv[nf] = attsrc[head * 64 + nf * 16 + l15];
      dv[nf] = attdst[head * 64 + nf * 16 + l15];
    }
#pragma unroll
    for (int mf = 0; mf < 8; mf++) {
#pragma unroll
      for (int r = 0; r < 4; r++) {
        float ps = 0.f, pd = 0.f;
#pragma unroll
        for (int nf = 0; nf < 4; nf++) {
          ps += acc[mf][nf][r] * sv[nf];
          pd += acc[mf][nf][r] * dv[nf];
        }
#pragma unroll
        for (int off = 8; off >= 1; off >>= 1) {
          ps += __shfl_xor(ps, off);
          pd += __shfl_xor(pd, off);
        }
        if (l15 == 0) {
          const int row = row0 + mf * 16 + q * 4 + r;
          a_s[(size_t)row * 4 + head] = ps;
          a_d[(size_t)row * 4 + head] = pd;
        }
      }
    }
  }
}

// ---------------- stride-64 CSR scatter ----------------
__global__ void scatter0(const int* __restrict__ src, const int* __restrict__ dst,
                         int* __restrict__ cursor, int* __restrict__ csr) {
  int e = blockIdx.x * blockDim.x + threadIdx.x;
  if (e >= NE) return;
  int d = dst[e];
  int pos = atomicAdd(&cursor[d], 1);
  if (pos < 64) csr[(size_t)d * 64 + pos] = src[e];
}

__global__ void scatter1(const int* __restrict__ src, const int* __restrict__ dst,
                         const int* __restrict__ newid,
                         int* __restrict__ cursor, int* __restrict__ csr) {
  int e = blockIdx.x * blockDim.x + threadIdx.x;
  if (e >= NE) return;
  int s = newid[src[e]], d = newid[dst[e]];
  if (s < 0 || d < 0) return;
  int pos = atomicAdd(&cursor[d], 1);
  if (pos < 64) csr[(size_t)d * 64 + pos] = s;
}

// --------- per-dest-node GAT: 4 nodes/wave, 16 lanes each, chunked deg<=64 --
// Each 16-lane group handles its node's edges in ceil(dim/16) chunks of 16
// (online over chunk registers, static-indexed). No wave-level fallback.
__global__ __launch_bounds__(256) void gat_node16(
    const int* __restrict__ cursor, const int* __restrict__ csr,
    const float* __restrict__ a_s, const float* __restrict__ a_d,
    const float* __restrict__ hW, const float* __restrict__ bias,
    const float* __restrict__ pool_w, const float* __restrict__ inv_norm,
    float* __restrict__ out, float* __restrict__ score, int bpgl) {
  const int lane = threadIdx.x & 63;
  const int wv = threadIdx.x >> 6;
  const int dbase = swz_block(blockIdx.x, bpgl) * 16 + wv * 4;
  const int p = lane >> 4, l16 = lane & 15;

  const int d = dbase + p;
  const int deg = min(cursor[d], 63);
  const int dim = deg + 1;  // + self loop

  // wave-uniform max dim -> chunk count (1..4)
  int dmaxw = dim;
  dmaxw = max(dmaxw, __shfl_xor(dmaxw, 16));
  dmaxw = max(dmaxw, __shfl_xor(dmaxw, 32));
  const int nch = (dmaxw + 15) >> 4;

  const float4 ad4 = *reinterpret_cast<const float4*>(&a_d[(size_t)d * 4]);

  // per-chunk edge source + logits (masked lanes -> -1e30)
  int sreg[4];
  float L0[4], L1[4], L2[4], L3[4];
#pragma unroll
  for (int c = 0; c < 4; c++) {
    if (c < nch) {
      const int j = c * 16 + l16;
      const bool has = j < dim;
      int s = (j < deg) ? csr[(size_t)d * 64 + j] : d;
      sreg[c] = s;
      float4 as4 = *reinterpret_cast<const float4*>(&a_s[(size_t)s * 4]);
      L0[c] = has ? leakyrelu(as4.x + ad4.x) : -1e30f;
      L1[c] = has ? leakyrelu(as4.y + ad4.y) : -1e30f;
      L2[c] = has ? leakyrelu(as4.z + ad4.z) : -1e30f;
      L3[c] = has ? leakyrelu(as4.w + ad4.w) : -1e30f;
    } else {
      sreg[c] = d;
      L0[c] = -1e30f; L1[c] = -1e30f; L2[c] = -1e30f; L3[c] = -1e30f;
    }
  }
  // per-head max: across chunks then across 16-lane group
  float m0 = fmaxf(fmaxf(L0[0], L0[1]), fmaxf(L0[2], L0[3]));
  float m1 = fmaxf(fmaxf(L1[0], L1[1]), fmaxf(L1[2], L1[3]));
  float m2 = fmaxf(fmaxf(L2[0], L2[1]), fmaxf(L2[2], L2[3]));
  float m3 = fmaxf(fmaxf(L3[0], L3[1]), fmaxf(L3[2], L3[3]));
#pragma unroll
  for (int off = 1; off <= 8; off <<= 1) {
    m0 = fmaxf(m0, __shfl_xor(m0, off));
    m1 = fmaxf(m1, __shfl_xor(m1, off));
    m2 = fmaxf(m2, __shfl_xor(m2, off));
    m3 = fmaxf(m3, __shfl_xor(m3, off));
  }
  // exponentials per chunk (masked -> exp(-huge)=0)
  float e0[4], e1[4], e2[4], e3[4];
  float dn0 = 0.f, dn1 = 0.f, dn2 = 0.f, dn3 = 0.f;
#pragma unroll
  for (int c = 0; c < 4; c++) {
    if (c < nch) {
      e0[c] = __expf(L0[c] - m0);
      e1[c] = __expf(L1[c] - m1);
      e2[c] = __expf(L2[c] - m2);
      e3[c] = __expf(L3[c] - m3);
      dn0 += e0[c]; dn1 += e1[c]; dn2 += e2[c]; dn3 += e3[c];
    } else {
      e0[c] = 0.f; e1[c] = 0.f; e2[c] = 0.f; e3[c] = 0.f;
    }
  }
#pragma unroll
  for (int off = 1; off <= 8; off <<= 1) {
    dn0 += __shfl_xor(dn0, off);
    dn1 += __shfl_xor(dn1, off);
    dn2 += __shfl_xor(dn2, off);
    dn3 += __shfl_xor(dn3, off);
  }

  // aggregation: lane owns cols {h*64 + l16*4 ..+3} for all 4 heads
  float4 acc[4];
#pragma unroll
  for (int h = 0; h < 4; h++) acc[h] = float4{0.f, 0.f, 0.f, 0.f};
#pragma unroll
  for (int c = 0; c < 4; c++) {
    if (c < nch) {
      const int tmax = min(16, dmaxw - c * 16);
#pragma unroll 2
      for (int tt = 0; tt < tmax; tt++) {
        const int idx = p * 16 + tt;
        int st = __shfl(sreg[c], idx);
        float c0 = __shfl(e0[c], idx), c1 = __shfl(e1[c], idx);
        float c2 = __shfl(e2[c], idx), c3 = __shfl(e3[c], idx);
        if (c * 16 + tt < dim) {
          const float4* hp = reinterpret_cast<const float4*>(&hW[(size_t)st * 256]) + l16;
          acc[0] = f4fma(hp[0],  c0, acc[0]);
          acc[1] = f4fma(hp[16], c1, acc[1]);
          acc[2] = f4fma(hp[32], c2, acc[2]);
          acc[3] = f4fma(hp[48], c3, acc[3]);
        }
      }
    }
  }

  const float inv[4] = {1.f / (dn0 + 1e-16f), 1.f / (dn1 + 1e-16f),
                        1.f / (dn2 + 1e-16f), 1.f / (dn3 + 1e-16f)};
  float sd = 0.f;
#pragma unroll
  for (int h = 0; h < 4; h++) {
    const int coff = h * 64 + l16 * 4;
    float4 bb = *reinterpret_cast<const float4*>(&bias[coff]);
    float4 o;
    o.x = eluf(acc[h].x * inv[h] + bb.x);
    o.y = eluf(acc[h].y * inv[h] + bb.y);
    o.z = eluf(acc[h].z * inv[h] + bb.z);
    o.w = eluf(acc[h].w * inv[h] + bb.w);
    *reinterpret_cast<float4*>(&out[(size_t)d * 256 + coff]) = o;
    float4 pw = *reinterpret_cast<const float4*>(&pool_w[coff]);
    sd += o.x * pw.x + o.y * pw.y + o.z * pw.z + o.w * pw.w;
  }
#pragma unroll
  for (int off = 1; off <= 8; off <<= 1) sd += __shfl_xor(sd, off);
  if (l16 == 0) score[d] = sd * inv_norm[0];
}

// ---------------- per-graph bitonic top-k sort ----------------
__global__ __launch_bounds__(1024) void topk_sort(const float* __restrict__ score,
                                                  int npg, int k,
                                                  int* __restrict__ perm,
                                                  int* __restrict__ newid) {
  __shared__ float sv[2048];
  __shared__ int si[2048];
  int g = blockIdx.x;
  for (int i = threadIdx.x; i < npg; i += blockDim.x) {
    sv[i] = score[(size_t)g * npg + i];
    si[i] = i;
  }
  __syncthreads();
  for (int size = 2; size <= npg; size <<= 1) {
    for (int stride = size >> 1; stride > 0; stride >>= 1) {
      for (int i = threadIdx.x; i < npg; i += blockDim.x) {
        int j = i ^ stride;
        if (j > i) {
          bool desc = ((i & size) == 0);
          float vi = sv[i], vj = sv[j];
          int ii = si[i], ij = si[j];
          bool i_before_j = (vi > vj) || (vi == vj && ii < ij);
          bool doswap = desc ? !i_before_j : i_before_j;
          if (doswap) { sv[i] = vj; sv[j] = vi; si[i] = ij; si[j] = ii; }
        }
      }
      __syncthreads();
    }
  }
  for (int j = threadIdx.x; j < k; j += blockDim.x) {
    int node = g * npg + si[j];
    perm[g * k + j] = node;
    if (newid) newid[node] = g * k + j;
  }
}

// ------- pooled gather + gate dot; emits hi/lo bf16 slabs for next GEMM -----
__global__ void gather_pool(const float* __restrict__ hx, const int* __restrict__ perm,
                            const float* __restrict__ score,
                            const float* __restrict__ gate_w, const float* __restrict__ gate_b,
                            unsigned short* __restrict__ xshi, unsigned short* __restrict__ xslo,
                            float* __restrict__ gate, int nrows, int bpgl) {
  int j = swz_block(blockIdx.x, bpgl) * 4 + (threadIdx.x >> 6);
  int lane = threadIdx.x & 63;
  if (j >= nrows) return;
  int node = perm[j];
  float tsc = tanhf(score[node]);
  float4 v = reinterpret_cast<const float4*>(&hx[(size_t)node * 256])[lane];
  v.x *= tsc; v.y *= tsc; v.z *= tsc; v.w *= tsc;
  ushort4 h4, l4;
  h4.x = f2bf(v.x); l4.x = f2bf(v.x - bf2f(h4.x));
  h4.y = f2bf(v.y); l4.y = f2bf(v.y - bf2f(h4.y));
  h4.z = f2bf(v.z); l4.z = f2bf(v.z - bf2f(h4.z));
  h4.w = f2bf(v.w); l4.w = f2bf(v.w - bf2f(h4.w));
  *reinterpret_cast<ushort4*>(&xshi[(size_t)j * 256 + lane * 4]) = h4;
  *reinterpret_cast<ushort4*>(&xslo[(size_t)j * 256 + lane * 4]) = l4;
  float4 gw = reinterpret_cast<const float4*>(gate_w)[lane];
  float gd = v.x * gw.x + v.y * gw.y + v.z * gw.z + v.w * gw.w;
#pragma unroll
  for (int off = 32; off >= 1; off >>= 1) gd += __shfl_xor(gd, off);
  if (lane == 0) gate[j] = gd + gate_b[0];
}

// ---- attention pooling: per-block softmax recompute + partial col sums -----
__global__ __launch_bounds__(256) void attpool_sum(const unsigned short* __restrict__ xhi,
                                                   const unsigned short* __restrict__ xlo,
                                                   const float* __restrict__ gate,
                                                   float* __restrict__ partials,
                                                   int npg, int nch) {
  int g = blockIdx.x / nch, sub = blockIdx.x % nch;
  int tid = threadIdx.x;
  __shared__ float red[256];
  size_t base = (size_t)g * npg;
  // recompute this graph's softmax stats (gates are L2-hot, 4KB)
  float m = -1e30f;
  for (int i = tid; i < npg; i += 256) m = fmaxf(m, gate[base + i]);
  red[tid] = m;
  __syncthreads();
  for (int s = 128; s >= 1; s >>= 1) {
    if (tid < s) red[tid] = fmaxf(red[tid], red[tid + s]);
    __syncthreads();
  }
  m = red[0];
  __syncthreads();
  float ss = 0.f;
  for (int i = tid; i < npg; i += 256) ss += __expf(gate[base + i] - m);
  red[tid] = ss;
  __syncthreads();
  for (int s = 128; s >= 1; s >>= 1) {
    if (tid < s) red[tid] += red[tid + s];
    __syncthreads();
  }
  float inv = 1.f / red[0];
  __syncthreads();
  // weighted column sum over this block's 32 rows
  size_t r0 = base + sub * 32;
  int c = tid;
  float a = 0.f;
#pragma unroll 8
  for (int i = 0; i < 32; i++) {
    float wv = __expf(gate[r0 + i] - m) * inv;
    float v = bf2f(xhi[(r0 + i) * 256 + c]) + bf2f(xlo[(r0 + i) * 256 + c]);
    a += wv * v;
  }
  partials[(size_t)blockIdx.x * 256 + c] = a;
}

__global__ __launch_bounds__(256) void attpool_reduce(const float* __restrict__ partials,
                                                      float* __restrict__ out,
                                                      int nch, int acc_flag) {
  int g = blockIdx.x, c = threadIdx.x;
  float a = 0.f;
  for (int s = 0; s < nch; s++) a += partials[((size_t)g * nch + s) * 256 + c];
  if (acc_flag) out[g * 256 + c] += a;
  else out[g * 256 + c] = a;
}

}  // namespace

extern "C" void kernel_launch(void* const* d_in, const int* in_sizes, int n_in,
                              void* d_out, int out_size, void* d_ws, size_t ws_size,
                              hipStream_t stream) {
  (void)in_sizes; (void)n_in; (void)out_size; (void)ws_size;
  const float* x       = (const float*)d_in[0];
  const int*   ei      = (const int*)d_in[1];
  const float* lin0_w  = (const float*)d_in[2];
  const float* lin0_b  = (const float*)d_in[3];
  const float* gat0_W  = (const float*)d_in[4];
  const float* gat0_as = (const float*)d_in[5];
  const float* gat0_ad = (const float*)d_in[6];
  const float* gat0_b  = (const float*)d_in[7];
  const float* pool0_w = (const float*)d_in[8];
  const float* gat1_W  = (const float*)d_in[9];
  const float* gat1_as = (const float*)d_in[10];
  const float* gat1_ad = (const float*)d_in[11];
  const float* gat1_b  = (const float*)d_in[12];
  const float* pool1_w = (const float*)d_in[13];
  const float* gate_w  = (const float*)d_in[14];
  const float* gate_b  = (const float*)d_in[15];
  float* out = (float*)d_out;
  const int* srcp = ei;
  const int* dstp = ei + NE;

  char* wsb = (char*)d_ws;
  size_t cur = 0;
  auto alloc = [&](size_t bytes) {
    void* p = wsb + cur;
    cur = (cur + bytes + 255) & ~(size_t)255;
    return p;
  };
  char* regA = (char*)alloc((size_t)NN0 * 256 * 4);        // hhi/hlo -> out0 -> {hW1,out1}
  char* regB = (char*)alloc((size_t)NN0 * 256 * 4);        // hW0 -> xs1hi/lo
  char* regD = (char*)alloc((size_t)NN0 * KP * 2 * 2);     // xhi/xlo -> xs0hi/lo
  float* a_s     = (float*)alloc((size_t)NN0 * 4 * 4);
  float* a_d     = (float*)alloc((size_t)NN0 * 4 * 4);
  int*   cursor  = (int*)alloc((size_t)NN0 * 4);
  int*   cursor2 = (int*)alloc((size_t)32768 * 4);
  int*   csr     = (int*)alloc((size_t)NN0 * 64 * 4);
  float* score   = (float*)alloc((size_t)NN0 * 4);
  int*   newid   = (int*)alloc((size_t)NN0 * 4);
  int*   perm    = (int*)alloc((size_t)NB * 1024 * 4);
  float* gateb   = (float*)alloc((size_t)32768 * 4);
  float* partials= (float*)alloc((size_t)NB * 32 * 256 * 4);
  float* norms   = (float*)alloc(2 * 4);
  unsigned short* whi0 = (unsigned short*)alloc((size_t)5 * 8192 * 2);
  unsigned short* wlo0 = (unsigned short*)alloc((size_t)5 * 8192 * 2);
  unsigned short* whi1 = (unsigned short*)alloc((size_t)8 * 8192 * 2);
  unsigned short* wlo1 = (unsigned short*)alloc((size_t)8 * 8192 * 2);
  unsigned short* whi2 = (unsigned short*)alloc((size_t)8 * 8192 * 2);
  unsigned short* wlo2 = (unsigned short*)alloc((size_t)8 * 8192 * 2);

  unsigned short* xhi = (unsigned short*)regD;
  unsigned short* xlo = xhi + (size_t)NN0 * KP;
  unsigned short* hhi = (unsigned short*)regA;
  unsigned short* hlo = hhi + (size_t)NN0 * 256;
  float* hW0  = (float*)regB;
  float* out0 = (float*)regA;
  unsigned short* xs0hi = (unsigned short*)regD;
  unsigned short* xs0lo = xs0hi + (size_t)32768 * 256;
  float* hW1  = (float*)regA;
  float* out1 = (float*)(regA + (size_t)32768 * 256 * 4);
  unsigned short* xs1hi = (unsigned short*)regB;
  unsigned short* xs1lo = xs1hi + (size_t)16384 * 256;

  // ---- merged prep ----
  {
    int grid = NN0 * KP / 256 + 160 + 256 + 256 + 256 + 1;
    prep<<<grid, 256, 0, stream>>>(x, lin0_w, gat0_W, gat1_W, pool0_w, pool1_w,
                                   xhi, xlo, whi0, wlo0, whi1, wlo1, whi2, wlo2,
                                   norms, cursor, cursor2, newid);
  }

  // ---- lin0 + ReLU -> hhi/hlo ----
  gemm_mfma<5, true, false><<<NN0 / 128, 256, 0, stream>>>(
      xhi, xlo, KP, whi0, wlo0, lin0_b, nullptr, hhi, hlo,
      nullptr, nullptr, nullptr, nullptr);

  // ---- GAT0: CSR + GEMM + node aggregation ----
  scatter0<<<NE / 256, 256, 0, stream>>>(srcp, dstp, cursor, csr);
  gemm_mfma<8, false, true><<<NN0 / 128, 256, 0, stream>>>(
      hhi, hlo, 256, whi1, wlo1, nullptr, hW0, nullptr, nullptr,
      gat0_as, gat0_ad, a_s, a_d);
  gat_node16<<<NN0 / 16, 256, 0, stream>>>(cursor, csr, a_s, a_d, hW0,
                                           gat0_b, pool0_w, norms, out0, score, 7);

  // ---- pool0: top-1024 of 2048 per graph ----
  topk_sort<<<NB, 1024, 0, stream>>>(score, 2048, 1024, perm, newid);
  gather_pool<<<32768 / 4, 256, 0, stream>>>(out0, perm, score, gate_w, gate_b,
                                             xs0hi, xs0lo, gateb, 32768, 8);
  attpool_sum<<<NB * 32, 256, 0, stream>>>(xs0hi, xs0lo, gateb, partials, 1024, 32);
  attpool_reduce<<<NB, 256, 0, stream>>>(partials, out, 32, 0);

  // ---- GAT1: fused remap+scatter (cursor2 pre-zeroed), GEMM, aggregation ----
  scatter1<<<NE / 256, 256, 0, stream>>>(srcp, dstp, newid, cursor2, csr);
  gemm_mfma<8, false, true><<<32768 / 128, 256, 0, stream>>>(
      xs0hi, xs0lo, 256, whi2, wlo2, nullptr, hW1, nullptr, nullptr,
      gat1_as, gat1_ad, a_s, a_d);
  gat_node16<<<32768 / 16, 256, 0, stream>>>(cursor2, csr, a_s, a_d, hW1,
                                             gat1_b, pool1_w, norms + 1, out1, score, 6);

  // ---- pool1: top-512 of 1024 per graph ----
  topk_sort<<<NB, 1024, 0, stream>>>(score, 1024, 512, perm, nullptr);
  gather_pool<<<16384 / 4, 256, 0, stream>>>(out1, perm, score, gate_w, gate_b,
                                             xs1hi, xs1lo, gateb, 16384, 7);
  attpool_sum<<<NB * 16, 256, 0, stream>>>(xs1hi, xs1lo, gateb, partials, 512, 16);
  attpool_reduce<<<NB, 256, 0, stream>>>(partials, out, 16, 1);
}

// Round 12
// 314.766 us; speedup vs baseline: 1.1453x; 1.0353x over previous
//
#include <hip/hip_runtime.h>
#include <cmath>

namespace {

constexpr int NN0 = 65536;   // nodes stage 0
constexpr int NB  = 32;      // graphs
constexpr int NE  = 524288;  // edges
constexpr int FIN = 129;
constexpr int KP  = 160;     // padded K for lin0 (5 k-tiles of 32)

typedef short bf16x8 __attribute__((ext_vector_type(8)));
typedef float f32x4 __attribute__((ext_vector_type(4)));

__device__ inline float leakyrelu(float z) { return z > 0.f ? z : 0.2f * z; }
__device__ inline float eluf(float z) { return z > 0.f ? z : expm1f(z); }

__device__ inline unsigned short f2bf(float x) {
  union { float f; unsigned int u; } v; v.f = x;
  unsigned int r = v.u + 0x7fffu + ((v.u >> 16) & 1u);
  return (unsigned short)(r >> 16);
}
__device__ inline float bf2f(unsigned short h) {
  union { unsigned int u; float f; } v; v.u = ((unsigned int)h) << 16;
  return v.f;
}

__device__ inline float4 f4fma(float4 a, float c, float4 acc) {
  acc.x += a.x * c; acc.y += a.y * c; acc.z += a.z * c; acc.w += a.w * c;
  return acc;
}

// XCD-aware block swizzle (bijective; NB%8==0)
__device__ inline int swz_block(int bid, int bpgl) {
  int x = bid & 7;
  int local = bid >> 3;
  int g = x + ((local >> bpgl) << 3);
  return (g << bpgl) + (local & ((1 << bpgl) - 1));
}

__device__ __forceinline__ void gload_lds16(const unsigned short* g, unsigned short* l) {
  __builtin_amdgcn_global_load_lds((const unsigned int*)g, (unsigned int*)l, 16, 0, 0);
}

// ---------------- merged prep: pack_x + 3x pack_w + norms + inits ----------
__device__ inline void pack_w_body(const float* __restrict__ W, int Kreal, int idx,
                                   unsigned short* __restrict__ hi,
                                   unsigned short* __restrict__ lo) {
  int j = idx & 7;
  int lane = (idx >> 3) & 63;
  int ct = (idx >> 9) & 15;
  int kt = idx >> 13;
  int k = kt * 32 + ((lane >> 4) << 3) + j;
  int c = ct * 16 + (lane & 15);
  float v = (k < Kreal) ? W[(size_t)k * 256 + c] : 0.f;
  unsigned short h = f2bf(v);
  hi[idx] = h;
  lo[idx] = f2bf(v - bf2f(h));
}

__global__ void prep(const float* __restrict__ x,
                     const float* __restrict__ w0, const float* __restrict__ w1,
                     const float* __restrict__ w2,
                     const float* __restrict__ pw0, const float* __restrict__ pw1,
                     unsigned short* __restrict__ xhi, unsigned short* __restrict__ xlo,
                     unsigned short* __restrict__ whi0, unsigned short* __restrict__ wlo0,
                     unsigned short* __restrict__ whi1, unsigned short* __restrict__ wlo1,
                     unsigned short* __restrict__ whi2, unsigned short* __restrict__ wlo2,
                     float* __restrict__ norms, int* __restrict__ cursor,
                     int* __restrict__ cursor2, int* __restrict__ newid) {
  const int NX = NN0 * KP / 256;   // 40960 blocks: pack x
  const int NW0 = 5 * 8192 / 256;  // 160
  const int NW = 8 * 8192 / 256;   // 256
  const int NC = NN0 / 256;        // 256: cursor/newid init
  int b = blockIdx.x, tid = threadIdx.x;
  if (b < NX) {
    int idx = b * 256 + tid;
    int row = idx / KP, c = idx - row * KP;
    float v = (c < FIN) ? x[(size_t)row * FIN + c] : 0.f;
    unsigned short h = f2bf(v);
    xhi[idx] = h;
    xlo[idx] = f2bf(v - bf2f(h));
    return;
  }
  b -= NX;
  if (b < NW0) { pack_w_body(w0, FIN, b * 256 + tid, whi0, wlo0); return; }
  b -= NW0;
  if (b < NW) { pack_w_body(w1, 256, b * 256 + tid, whi1, wlo1); return; }
  b -= NW;
  if (b < NW) { pack_w_body(w2, 256, b * 256 + tid, whi2, wlo2); return; }
  b -= NW;
  if (b < NC) {
    int i = b * 256 + tid;
    cursor[i] = 0;
    newid[i] = -1;
    if (i < 32768) cursor2[i] = 0;
    return;
  }
  if (tid < 64) {
    float a0 = 0.f, a1 = 0.f;
#pragma unroll
    for (int j = tid; j < 256; j += 64) {
      float v0 = pw0[j]; a0 += v0 * v0;
      float v1 = pw1[j]; a1 += v1 * v1;
    }
#pragma unroll
    for (int off = 32; off >= 1; off >>= 1) {
      a0 += __shfl_xor(a0, off);
      a1 += __shfl_xor(a1, off);
    }
    if (tid == 0) {
      norms[0] = 1.f / (sqrtf(a0) + 1e-16f);
      norms[1] = 1.f / (sqrtf(a1) + 1e-16f);
    }
  }
}

// ---------------- split-bf16 3-pass MFMA GEMM, BM=128 x BN=256 --------------
// INDIR: A rows gathered via rowmap[]; output + a_s/a_d scaled by tscale[row].
template <int KT, bool RELUBIAS, bool ATT, bool INDIR>
__global__ __launch_bounds__(256, 2) void gemm_mfma(
    const unsigned short* __restrict__ Xhi, const unsigned short* __restrict__ Xlo,
    int ldx,
    const unsigned short* __restrict__ Bhi, const unsigned short* __restrict__ Blo,
    const float* __restrict__ bias,
    float* __restrict__ Out,
    unsigned short* __restrict__ OutHi, unsigned short* __restrict__ OutLo,
    const float* __restrict__ attsrc, const float* __restrict__ attdst,
    float* __restrict__ a_s, float* __restrict__ a_d,
    const int* __restrict__ rowmap, const float* __restrict__ tscale, int swzl) {
  __shared__ __align__(16) unsigned short As[2][2][128][32];  // 32 KB
  const int tid = threadIdx.x;
  const int lane = tid & 63;
  const int w = tid >> 6;
  const int rb = (swzl >= 0) ? swz_block(blockIdx.x, swzl) : blockIdx.x;
  const int row0 = rb * 128;
  const int l15 = lane & 15, q = lane >> 4;
  const int sl4 = lane >> 2;
  const int skc = (lane & 3) * 8;

  size_t gr[2];
#pragma unroll
  for (int i = 0; i < 2; i++) {
    int lr = row0 + (w + 4 * i) * 16 + sl4;
    gr[i] = INDIR ? (size_t)rowmap[lr] : (size_t)lr;
  }

  auto stage = [&](int nb, int kt) {
#pragma unroll
    for (int i = 0; i < 2; i++) {
      const int rbase = (w + 4 * i) * 16;
      const size_t goff = gr[i] * ldx + kt * 32 + skc;
      gload_lds16(Xhi + goff, &As[nb][0][rbase][0]);
      gload_lds16(Xlo + goff, &As[nb][1][rbase][0]);
    }
  };

  f32x4 acc[8][4];
#pragma unroll
  for (int mf = 0; mf < 8; mf++)
#pragma unroll
    for (int nf = 0; nf < 4; nf++) acc[mf][nf] = (f32x4)(0.f);

  stage(0, 0);
  __syncthreads();

#pragma unroll
  for (int kt = 0; kt < KT; ++kt) {
    const int nb = kt & 1;
    if (kt + 1 < KT) stage(nb ^ 1, kt + 1);
    bf16x8 bh[4], bl[4];
#pragma unroll
    for (int nf = 0; nf < 4; nf++) {
      const int ct = w * 4 + nf;
      const size_t bbase = ((size_t)((kt * 16 + ct) * 64 + lane)) << 3;
      bh[nf] = *reinterpret_cast<const bf16x8*>(Bhi + bbase);
      bl[nf] = *reinterpret_cast<const bf16x8*>(Blo + bbase);
    }
#pragma unroll
    for (int mf = 0; mf < 8; mf++) {
      const int ar = mf * 16 + l15;
      bf16x8 ah = *reinterpret_cast<const bf16x8*>(&As[nb][0][ar][q * 8]);
      bf16x8 al = *reinterpret_cast<const bf16x8*>(&As[nb][1][ar][q * 8]);
#pragma unroll
      for (int nf = 0; nf < 4; nf++) {
        acc[mf][nf] = __builtin_amdgcn_mfma_f32_16x16x32_bf16(ah, bh[nf], acc[mf][nf], 0, 0, 0);
        acc[mf][nf] = __builtin_amdgcn_mfma_f32_16x16x32_bf16(ah, bl[nf], acc[mf][nf], 0, 0, 0);
        acc[mf][nf] = __builtin_amdgcn_mfma_f32_16x16x32_bf16(al, bh[nf], acc[mf][nf], 0, 0, 0);
      }
    }
    __syncthreads();
  }

#pragma unroll
  for (int mf = 0; mf < 8; mf++) {
    const int rowb = row0 + mf * 16 + q * 4;
#pragma unroll
    for (int r = 0; r < 4; r++) {
      const float ts = INDIR ? tscale[rowb + r] : 1.f;
#pragma unroll
      for (int nf = 0; nf < 4; nf++) {
        float v = acc[mf][nf][r];
        const int col = w * 64 + nf * 16 + l15;
        if constexpr (RELUBIAS) {
          v += bias[col];
          v = fmaxf(v, 0.f);
          unsigned short h = f2bf(v);
          OutHi[(size_t)(rowb + r) * 256 + col] = h;
          OutLo[(size_t)(rowb + r) * 256 + col] = f2bf(v - bf2f(h));
        } else {
          if constexpr (INDIR) v *= ts;
          Out[(size_t)(rowb + r) * 256 + col] = v;
        }
      }
    }
  }
  if constexpr (ATT) {
    const int head = w;
    float sv[4], dv[4];
#pragma unroll
    for (int nf = 0; nf < 4; nf++) {
      sv[nf] = attsrc[head * 64 + nf * 16 + l15];
      dv[nf] = attdst[head * 64 + nf * 16 + l15];
    }
#pragma unroll
    for (int mf = 0; mf < 8; mf++) {
#pragma unroll
      for (int r = 0; r < 4; r++) {
        float ps = 0.f, pd = 0.f;
#pragma unroll
        for (int nf = 0; nf < 4; nf++) {
          ps += acc[mf][nf][r] * sv[nf];
          pd += acc[mf][nf][r] * dv[nf];
        }
#pragma unroll
        for (int off = 8; off >= 1; off >>= 1) {
          ps += __shfl_xor(ps, off);
          pd += __shfl_xor(pd, off);
        }
        if (l15 == 0) {
          const int row = row0 + mf * 16 + q * 4 + r;
          float ts = INDIR ? tscale[row] : 1.f;
          a_s[(size_t)row * 4 + head] = ps * ts;
          a_d[(size_t)row * 4 + head] = pd * ts;
        }
      }
    }
  }
}

// ---------------- stride-64 CSR scatter ----------------
__global__ void scatter0(const int* __restrict__ src, const int* __restrict__ dst,
                         int* __restrict__ cursor, int* __restrict__ csr) {
  int e = blockIdx.x * blockDim.x + threadIdx.x;
  if (e >= NE) return;
  int d = dst[e];
  int pos = atomicAdd(&cursor[d], 1);
  if (pos < 64) csr[(size_t)d * 64 + pos] = src[e];
}

__global__ void scatter1(const int* __restrict__ src, const int* __restrict__ dst,
                         const int* __restrict__ newid,
                         int* __restrict__ cursor, int* __restrict__ csr) {
  int e = blockIdx.x * blockDim.x + threadIdx.x;
  if (e >= NE) return;
  int s = newid[src[e]], d = newid[dst[e]];
  if (s < 0 || d < 0) return;
  int pos = atomicAdd(&cursor[d], 1);
  if (pos < 64) csr[(size_t)d * 64 + pos] = s;
}

// --------- per-dest-node GAT: 4 nodes/wave, 16 lanes each, chunked deg<=64 --
// Writes output as hi/lo bf16 slabs; fused pool-score and raw gate dots.
__global__ __launch_bounds__(256) void gat_node16(
    const int* __restrict__ cursor, const int* __restrict__ csr,
    const float* __restrict__ a_s, const float* __restrict__ a_d,
    const float* __restrict__ hW, const float* __restrict__ bias,
    const float* __restrict__ pool_w, const float* __restrict__ inv_norm,
    const float* __restrict__ gate_w,
    unsigned short* __restrict__ outHi, unsigned short* __restrict__ outLo,
    float* __restrict__ score, float* __restrict__ graw, int bpgl) {
  const int lane = threadIdx.x & 63;
  const int wv = threadIdx.x >> 6;
  const int dbase = swz_block(blockIdx.x, bpgl) * 16 + wv * 4;
  const int p = lane >> 4, l16 = lane & 15;

  const int d = dbase + p;
  const int deg = min(cursor[d], 63);
  const int dim = deg + 1;  // + self loop

  int dmaxw = dim;
  dmaxw = max(dmaxw, __shfl_xor(dmaxw, 16));
  dmaxw = max(dmaxw, __shfl_xor(dmaxw, 32));
  const int nch = (dmaxw + 15) >> 4;

  const float4 ad4 = *reinterpret_cast<const float4*>(&a_d[(size_t)d * 4]);

  int sreg[4];
  float L0[4], L1[4], L2[4], L3[4];
#pragma unroll
  for (int c = 0; c < 4; c++) {
    if (c < nch) {
      const int j = c * 16 + l16;
      const bool has = j < dim;
      int s = (j < deg) ? csr[(size_t)d * 64 + j] : d;
      sreg[c] = s;
      float4 as4 = *reinterpret_cast<const float4*>(&a_s[(size_t)s * 4]);
      L0[c] = has ? leakyrelu(as4.x + ad4.x) : -1e30f;
      L1[c] = has ? leakyrelu(as4.y + ad4.y) : -1e30f;
      L2[c] = has ? leakyrelu(as4.z + ad4.z) : -1e30f;
      L3[c] = has ? leakyrelu(as4.w + ad4.w) : -1e30f;
    } else {
      sreg[c] = d;
      L0[c] = -1e30f; L1[c] = -1e30f; L2[c] = -1e30f; L3[c] = -1e30f;
    }
  }
  float m0 = fmaxf(fmaxf(L0[0], L0[1]), fmaxf(L0[2], L0[3]));
  float m1 = fmaxf(fmaxf(L1[0], L1[1]), fmaxf(L1[2], L1[3]));
  float m2 = fmaxf(fmaxf(L2[0], L2[1]), fmaxf(L2[2], L2[3]));
  float m3 = fmaxf(fmaxf(L3[0], L3[1]), fmaxf(L3[2], L3[3]));
#pragma unroll
  for (int off = 1; off <= 8; off <<= 1) {
    m0 = fmaxf(m0, __shfl_xor(m0, off));
    m1 = fmaxf(m1, __shfl_xor(m1, off));
    m2 = fmaxf(m2, __shfl_xor(m2, off));
    m3 = fmaxf(m3, __shfl_xor(m3, off));
  }
  float e0[4], e1[4], e2[4], e3[4];
  float dn0 = 0.f, dn1 = 0.f, dn2 = 0.f, dn3 = 0.f;
#pragma unroll
  for (int c = 0; c < 4; c++) {
    if (c < nch) {
      e0[c] = __expf(L0[c] - m0);
      e1[c] = __expf(L1[c] - m1);
      e2[c] = __expf(L2[c] - m2);
      e3[c] = __expf(L3[c] - m3);
      dn0 += e0[c]; dn1 += e1[c]; dn2 += e2[c]; dn3 += e3[c];
    } else {
      e0[c] = 0.f; e1[c] = 0.f; e2[c] = 0.f; e3[c] = 0.f;
    }
  }
#pragma unroll
  for (int off = 1; off <= 8; off <<= 1) {
    dn0 += __shfl_xor(dn0, off);
    dn1 += __shfl_xor(dn1, off);
    dn2 += __shfl_xor(dn2, off);
    dn3 += __shfl_xor(dn3, off);
  }

  float4 acc[4];
#pragma unroll
  for (int h = 0; h < 4; h++) acc[h] = float4{0.f, 0.f, 0.f, 0.f};
#pragma unroll
  for (int c = 0; c < 4; c++) {
    if (c < nch) {
      const int tmax = min(16, dmaxw - c * 16);
#pragma unroll 2
      for (int tt = 0; tt < tmax; tt++) {
        const int idx = p * 16 + tt;
        int st = __shfl(sreg[c], idx);
        float c0 = __shfl(e0[c], idx), c1 = __shfl(e1[c], idx);
        float c2 = __shfl(e2[c], idx), c3 = __shfl(e3[c], idx);
        if (c * 16 + tt < dim) {
          const float4* hp = reinterpret_cast<const float4*>(&hW[(size_t)st * 256]) + l16;
          acc[0] = f4fma(hp[0],  c0, acc[0]);
          acc[1] = f4fma(hp[16], c1, acc[1]);
          acc[2] = f4fma(hp[32], c2, acc[2]);
          acc[3] = f4fma(hp[48], c3, acc[3]);
        }
      }
    }
  }

  const float inv[4] = {1.f / (dn0 + 1e-16f), 1.f / (dn1 + 1e-16f),
                        1.f / (dn2 + 1e-16f), 1.f / (dn3 + 1e-16f)};
  float sd = 0.f, gd = 0.f;
#pragma unroll
  for (int h = 0; h < 4; h++) {
    const int coff = h * 64 + l16 * 4;
    float4 bb = *reinterpret_cast<const float4*>(&bias[coff]);
    float4 o;
    o.x = eluf(acc[h].x * inv[h] + bb.x);
    o.y = eluf(acc[h].y * inv[h] + bb.y);
    o.z = eluf(acc[h].z * inv[h] + bb.z);
    o.w = eluf(acc[h].w * inv[h] + bb.w);
    ushort4 oh, ol;
    oh.x = f2bf(o.x); ol.x = f2bf(o.x - bf2f(oh.x));
    oh.y = f2bf(o.y); ol.y = f2bf(o.y - bf2f(oh.y));
    oh.z = f2bf(o.z); ol.z = f2bf(o.z - bf2f(oh.z));
    oh.w = f2bf(o.w); ol.w = f2bf(o.w - bf2f(oh.w));
    *reinterpret_cast<ushort4*>(&outHi[(size_t)d * 256 + coff]) = oh;
    *reinterpret_cast<ushort4*>(&outLo[(size_t)d * 256 + coff]) = ol;
    float4 pw = *reinterpret_cast<const float4*>(&pool_w[coff]);
    float4 gw = *reinterpret_cast<const float4*>(&gate_w[coff]);
    sd += o.x * pw.x + o.y * pw.y + o.z * pw.z + o.w * pw.w;
    gd += o.x * gw.x + o.y * gw.y + o.z * gw.z + o.w * gw.w;
  }
#pragma unroll
  for (int off = 1; off <= 8; off <<= 1) {
    sd += __shfl_xor(sd, off);
    gd += __shfl_xor(gd, off);
  }
  if (l16 == 0) {
    score[d] = sd * inv_norm[0];
    graw[d] = gd;
  }
}

// ------- per-graph bitonic top-k sort + fused gate/tscale emission ----------
__global__ __launch_bounds__(1024) void topk_sort(const float* __restrict__ score,
                                                  const float* __restrict__ graw,
                                                  const float* __restrict__ gate_b,
                                                  int npg, int k,
                                                  int* __restrict__ perm,
                                                  int* __restrict__ newid,
                                                  float* __restrict__ gate,
                                                  float* __restrict__ tsc) {
  __shared__ float sv[2048];
  __shared__ int si[2048];
  int g = blockIdx.x;
  for (int i = threadIdx.x; i < npg; i += blockDim.x) {
    sv[i] = score[(size_t)g * npg + i];
    si[i] = i;
  }
  __syncthreads();
  for (int size = 2; size <= npg; size <<= 1) {
    for (int stride = size >> 1; stride > 0; stride >>= 1) {
      for (int i = threadIdx.x; i < npg; i += blockDim.x) {
        int j = i ^ stride;
        if (j > i) {
          bool desc = ((i & size) == 0);
          float vi = sv[i], vj = sv[j];
          int ii = si[i], ij = si[j];
          bool i_before_j = (vi > vj) || (vi == vj && ii < ij);
          bool doswap = desc ? !i_before_j : i_before_j;
          if (doswap) { sv[i] = vj; sv[j] = vi; si[i] = ij; si[j] = ii; }
        }
      }
      __syncthreads();
    }
  }
  const float gb = gate_b[0];
  for (int j = threadIdx.x; j < k; j += blockDim.x) {
    int node = g * npg + si[j];
    perm[g * k + j] = node;
    if (newid) newid[node] = g * k + j;
    float ts = tanhf(sv[j]);
    tsc[g * k + j] = ts;
    gate[g * k + j] = ts * graw[node] + gb;
  }
}

// ---- attention pooling: softmax recompute + indirect partial col sums ------
__global__ __launch_bounds__(256) void attpool_sum(const unsigned short* __restrict__ xhi,
                                                   const unsigned short* __restrict__ xlo,
                                                   const int* __restrict__ perm,
                                                   const float* __restrict__ tsc,
                                                   const float* __restrict__ gate,
                                                   float* __restrict__ partials,
                                                   int npg, int bpgl) {
  int o = swz_block(blockIdx.x, bpgl);
  int g = o >> bpgl, sub = o & ((1 << bpgl) - 1);
  int tid = threadIdx.x;
  __shared__ float red[256];
  size_t base = (size_t)g * npg;
  float m = -1e30f;
  for (int i = tid; i < npg; i += 256) m = fmaxf(m, gate[base + i]);
  red[tid] = m;
  __syncthreads();
  for (int s = 128; s >= 1; s >>= 1) {
    if (tid < s) red[tid] = fmaxf(red[tid], red[tid + s]);
    __syncthreads();
  }
  m = red[0];
  __syncthreads();
  float ss = 0.f;
  for (int i = tid; i < npg; i += 256) ss += __expf(gate[base + i] - m);
  red[tid] = ss;
  __syncthreads();
  for (int s = 128; s >= 1; s >>= 1) {
    if (tid < s) red[tid] += red[tid + s];
    __syncthreads();
  }
  float inv = 1.f / red[0];
  __syncthreads();
  size_t r0 = base + sub * 32;
  int c = tid;
  float a = 0.f;
#pragma unroll 8
  for (int i = 0; i < 32; i++) {
    float wv = __expf(gate[r0 + i] - m) * inv * tsc[r0 + i];
    size_t node = (size_t)perm[r0 + i];
    float v = bf2f(xhi[node * 256 + c]) + bf2f(xlo[node * 256 + c]);
    a += wv * v;
  }
  partials[(size_t)o * 256 + c] = a;
}

__global__ __launch_bounds__(256) void attpool_reduce(const float* __restrict__ partials,
                                                      float* __restrict__ out,
                                                      int nch, int acc_flag) {
  int g = blockIdx.x, c = threadIdx.x;
  float a = 0.f;
  for (int s = 0; s < nch; s++) a += partials[((size_t)g * nch + s) * 256 + c];
  if (acc_flag) out[g * 256 + c] += a;
  else out[g * 256 + c] = a;
}

}  // namespace

extern "C" void kernel_launch(void* const* d_in, const int* in_sizes, int n_in,
                              void* d_out, int out_size, void* d_ws, size_t ws_size,
                              hipStream_t stream) {
  (void)in_sizes; (void)n_in; (void)out_size; (void)ws_size;
  const float* x       = (const float*)d_in[0];
  const int*   ei      = (const int*)d_in[1];
  const float* lin0_w  = (const float*)d_in[2];
  const float* lin0_b  = (const float*)d_in[3];
  const float* gat0_W  = (const float*)d_in[4];
  const float* gat0_as = (const float*)d_in[5];
  const float* gat0_ad = (const float*)d_in[6];
  const float* gat0_b  = (const float*)d_in[7];
  const float* pool0_w = (const float*)d_in[8];
  const float* gat1_W  = (const float*)d_in[9];
  const float* gat1_as = (const float*)d_in[10];
  const float* gat1_ad = (const float*)d_in[11];
  const float* gat1_b  = (const float*)d_in[12];
  const float* pool1_w = (const float*)d_in[13];
  const float* gate_w  = (const float*)d_in[14];
  const float* gate_b  = (const float*)d_in[15];
  float* out = (float*)d_out;
  const int* srcp = ei;
  const int* dstp = ei + NE;

  char* wsb = (char*)d_ws;
  size_t cur = 0;
  auto alloc = [&](size_t bytes) {
    void* p = wsb + cur;
    cur = (cur + bytes + 255) & ~(size_t)255;
    return p;
  };
  char* regA = (char*)alloc((size_t)NN0 * 256 * 4);        // hhi/hlo -> out0hi/lo
  char* regB = (char*)alloc((size_t)NN0 * 256 * 4);        // hW0 -> {hW1, out1hi/lo}
  char* regD = (char*)alloc((size_t)NN0 * KP * 2 * 2);     // xhi/xlo
  float* a_s     = (float*)alloc((size_t)NN0 * 4 * 4);
  float* a_d     = (float*)alloc((size_t)NN0 * 4 * 4);
  int*   cursor  = (int*)alloc((size_t)NN0 * 4);
  int*   cursor2 = (int*)alloc((size_t)32768 * 4);
  int*   csr     = (int*)alloc((size_t)NN0 * 64 * 4);
  float* score   = (float*)alloc((size_t)NN0 * 4);
  float* graw    = (float*)alloc((size_t)NN0 * 4);
  int*   newid   = (int*)alloc((size_t)NN0 * 4);
  int*   perm0   = (int*)alloc((size_t)32768 * 4);
  int*   perm1   = (int*)alloc((size_t)16384 * 4);
  float* tsc0    = (float*)alloc((size_t)32768 * 4);
  float* tsc1    = (float*)alloc((size_t)16384 * 4);
  float* gate0   = (float*)alloc((size_t)32768 * 4);
  float* gate1   = (float*)alloc((size_t)16384 * 4);
  float* partials= (float*)alloc((size_t)NB * 32 * 256 * 4);
  float* norms   = (float*)alloc(2 * 4);
  unsigned short* whi0 = (unsigned short*)alloc((size_t)5 * 8192 * 2);
  unsigned short* wlo0 = (unsigned short*)alloc((size_t)5 * 8192 * 2);
  unsigned short* whi1 = (unsigned short*)alloc((size_t)8 * 8192 * 2);
  unsigned short* wlo1 = (unsigned short*)alloc((size_t)8 * 8192 * 2);
  unsigned short* whi2 = (unsigned short*)alloc((size_t)8 * 8192 * 2);
  unsigned short* wlo2 = (unsigned short*)alloc((size_t)8 * 8192 * 2);

  unsigned short* xhi = (unsigned short*)regD;
  unsigned short* xlo = xhi + (size_t)NN0 * KP;
  unsigned short* hhi = (unsigned short*)regA;
  unsigned short* hlo = hhi + (size_t)NN0 * 256;
  float* hW0  = (float*)regB;
  unsigned short* out0hi = (unsigned short*)regA;          // overwrites hhi/hlo
  unsigned short* out0lo = out0hi + (size_t)NN0 * 256;
  float* hW1  = (float*)regB;                              // overwrites hW0
  unsigned short* out1hi = (unsigned short*)(regB + (size_t)32768 * 256 * 4);
  unsigned short* out1lo = out1hi + (size_t)32768 * 256;

  // ---- merged prep ----
  {
    int grid = NN0 * KP / 256 + 160 + 256 + 256 + 256 + 1;
    prep<<<grid, 256, 0, stream>>>(x, lin0_w, gat0_W, gat1_W, pool0_w, pool1_w,
                                   xhi, xlo, whi0, wlo0, whi1, wlo1, whi2, wlo2,
                                   norms, cursor, cursor2, newid);
  }

  // ---- lin0 + ReLU -> hhi/hlo ----
  gemm_mfma<5, true, false, false><<<NN0 / 128, 256, 0, stream>>>(
      xhi, xlo, KP, whi0, wlo0, lin0_b, nullptr, hhi, hlo,
      nullptr, nullptr, nullptr, nullptr, nullptr, nullptr, -1);

  // ---- GAT0: CSR + GEMM + node aggregation ----
  scatter0<<<NE / 256, 256, 0, stream>>>(srcp, dstp, cursor, csr);
  gemm_mfma<8, false, true, false><<<NN0 / 128, 256, 0, stream>>>(
      hhi, hlo, 256, whi1, wlo1, nullptr, hW0, nullptr, nullptr,
      gat0_as, gat0_ad, a_s, a_d, nullptr, nullptr, -1);
  gat_node16<<<NN0 / 16, 256, 0, stream>>>(cursor, csr, a_s, a_d, hW0,
                                           gat0_b, pool0_w, norms, gate_w,
                                           out0hi, out0lo, score, graw, 7);

  // ---- pool0: top-1024 of 2048 per graph (gate/tscale fused) ----
  topk_sort<<<NB, 1024, 0, stream>>>(score, graw, gate_b, 2048, 1024,
                                     perm0, newid, gate0, tsc0);
  attpool_sum<<<NB * 32, 256, 0, stream>>>(out0hi, out0lo, perm0, tsc0, gate0,
                                           partials, 1024, 5);
  attpool_reduce<<<NB, 256, 0, stream>>>(partials, out, 32, 0);

  // ---- GAT1: fused remap+scatter, indirect GEMM, aggregation ----
  scatter1<<<NE / 256, 256, 0, stream>>>(srcp, dstp, newid, cursor2, csr);
  gemm_mfma<8, false, true, true><<<32768 / 128, 256, 0, stream>>>(
      out0hi, out0lo, 256, whi2, wlo2, nullptr, hW1, nullptr, nullptr,
      gat1_as, gat1_ad, a_s, a_d, perm0, tsc0, 3);
  gat_node16<<<32768 / 16, 256, 0, stream>>>(cursor2, csr, a_s, a_d, hW1,
                                             gat1_b, pool1_w, norms + 1, gate_w,
                                             out1hi, out1lo, score, graw, 6);

  // ---- pool1: top-512 of 1024 per graph ----
  topk_sort<<<NB, 1024, 0, stream>>>(score, graw, gate_b, 1024, 512,
                                     perm1, nullptr, gate1, tsc1);
  attpool_sum<<<NB * 16, 256, 0, stream>>>(out1hi, out1lo, perm1, tsc1, gate1,
                                           partials, 512, 4);
  attpool_reduce<<<NB, 256, 0, stream>>>(partials, out, 16, 1);
}